// Round 9
// baseline (1679.845 us; speedup 1.0000x reference)
//
#include <hip/hip_runtime.h>
#include <hip/hip_bf16.h>
#include <math.h>

#define BB 32
#define SS 256
#define EE 512
#define HH 1024
#define LDM 256
#define NROW (BB*SS)   // 8192
#define NWG 64         // cooperative wgs for recurrence (1 per 4 CUs; all resident)

typedef __attribute__((ext_vector_type(8))) short bf16x8;
typedef __attribute__((ext_vector_type(4))) float f32x4;
typedef unsigned long long u64;

static __device__ inline unsigned short f2bf(float f){
  unsigned u = __float_as_uint(f);
  unsigned r = (u + 0x7fffu + ((u >> 16) & 1u)) >> 16;
  return (unsigned short)r;
}
// cheap round (no tie-to-even) for GEMM staging
static __device__ inline unsigned short f2bf_fast(float f){
  return (unsigned short)((__float_as_uint(f) + 0x8000u) >> 16);
}
static __device__ inline bf16x8 cvt8(float4 x, float4 y){
  union { ushort s[8]; bf16x8 v; } t;
  t.s[0]=f2bf_fast(x.x); t.s[1]=f2bf_fast(x.y); t.s[2]=f2bf_fast(x.z); t.s[3]=f2bf_fast(x.w);
  t.s[4]=f2bf_fast(y.x); t.s[5]=f2bf_fast(y.y); t.s[6]=f2bf_fast(y.z); t.s[7]=f2bf_fast(y.w);
  return t.v;
}
static __device__ inline unsigned packbf(float a, float b){
  return (unsigned)f2bf(a) | ((unsigned)f2bf(b) << 16);
}

// fast tanh: 1 - 2/(e^{2x}+1)
static __device__ inline float ftanh(float x){
  float e = __expf(2.f*x);
  return 1.f - 2.f/(e + 1.f);
}

// coherent (L1/L2-bypass, LLC-read) 16B load on the NORMAL coalescing path.
// Result lands asynchronously: caller must s_waitcnt vmcnt(0) + sched_barrier
// before first use.
#define GLD(dst, p) asm volatile("global_load_dwordx4 %0, %1, off sc0 sc1" \
                                 : "=v"(dst) : "v"(p) : "memory")

static __device__ inline bf16x8 asbf(f32x4 x){
  union { f32x4 f; bf16x8 b; } u; u.f = x; return u.b;
}

// ---------------- sort (stable argsort by descending length) ----------------
__global__ void k_sort(const int* __restrict__ length, int* __restrict__ sorted_idx){
  int b = threadIdx.x;
  if (b >= BB) return;
  int lb = length[b];
  int r = 0;
  for (int o = 0; o < BB; ++o){
    int lo = length[o];
    if (lo > lb || (lo == lb && o < b)) ++r;
  }
  sorted_idx[r] = b;
}

// token / target maps in sorted order
__global__ void k_maps(const int* __restrict__ sorted_idx,
                       const int* __restrict__ inp_seq, const int* __restrict__ tgt_seq,
                       int* __restrict__ tokmap, int* __restrict__ tgtmap){
  int bs = blockIdx.x; int t = threadIdx.x;
  int b = sorted_idx[bs];
  tokmap[bs*SS + t] = inp_seq[b*SS + t];
  tgtmap[bs*SS + t] = tgt_seq[b*SS + t];
}

// hid = z @ l2h_w.T + l2h_b, written DIRECTLY in bf16 fragment-major layout
__global__ __launch_bounds__(256) void k_hid(const float* __restrict__ z,
        const float* __restrict__ w, const float* __restrict__ bias,
        ushort* __restrict__ hb0){
  int id = blockIdx.x*256 + threadIdx.x;      // flat [B,2H] index = b*2048 + c
  int b = id >> 11, c = id & 2047;
  const float4* zr = (const float4*)(z + b*LDM);
  const float4* wr = (const float4*)(w + (size_t)c*LDM);
  float a0=0,a1=0,a2=0,a3=0;
  #pragma unroll 4
  for (int k=0;k<LDM/4;k++){ float4 zz=zr[k], ww=wr[k];
    a0+=zz.x*ww.x; a1+=zz.y*ww.y; a2+=zz.z*ww.z; a3+=zz.w*ww.w; }
  float val = a0+a1+a2+a3 + bias[c];
  int layer = id >> 15, bp = (id >> 10) & 31, j = id & 1023;
  hb0[(layer<<15) + ((j>>3)<<8) + (bp<<3) + (j&7)] = f2bf(val);
}

// concat [head_w(33); p0(256); p1(64); p2(16); zeros(15)] -> wcat[384][1024]
__global__ __launch_bounds__(256) void k_wcat(
    const float* __restrict__ head_w, const float* __restrict__ p0,
    const float* __restrict__ p1, const float* __restrict__ p2,
    float* __restrict__ wcat){
  int row = blockIdx.x; int t = threadIdx.x;
  float4* dst = (float4*)(wcat + (size_t)row*HH);
  const float* src;
  if      (row < 33)  src = head_w + (size_t)row*HH;
  else if (row < 289) src = p0 + (size_t)(row-33)*HH;
  else if (row < 353) src = p1 + (size_t)(row-289)*HH;
  else if (row < 369) src = p2 + (size_t)(row-353)*HH;
  else { dst[t] = make_float4(0.f,0.f,0.f,0.f); return; }
  dst[t] = ((const float4*)src)[t];
}

// bucket unmasked rows by target cluster (ballot-aggregated atomics)
__global__ __launch_bounds__(256) void k_bin(
    const int* __restrict__ tgtmap, int* __restrict__ cnt,
    int* __restrict__ l0, int* __restrict__ l1, int* __restrict__ l2)
{
  int row = blockIdx.x*256 + threadIdx.x;
  int tgt = tgtmap[row];
  int ci = (tgt == 0) ? -1 : (tgt >= 1000) ? 2 : (tgt >= 100) ? 1 : (tgt >= 30) ? 0 : -1;
  int lane = threadIdx.x & 63;
  #pragma unroll
  for (int c = 0; c < 3; ++c){
    unsigned long long mask = __ballot(ci == c);
    int nc = __popcll(mask);
    int base = 0;
    if (lane == 0 && nc) base = atomicAdd(&cnt[c], nc);
    base = __shfl(base, 0);
    if (ci == c){
      int pos = __popcll(mask & ((1ull << lane) - 1ull));
      int* lst = (c == 0) ? l0 : (c == 1) ? l1 : l2;
      lst[base + pos] = row;
    }
  }
}

// ---------------- bf16 MFMA GEMM: C[M,N] = A[M,K] @ Bm[N,K]^T (+bias0+bias1)
// abf16: A is already bf16 (ushort, row-major, lda elems) -> staging is a copy.
__global__ __launch_bounds__(256) void k_gemm_bf16(
    const float* __restrict__ A, int lda, const int* __restrict__ rowmap, int abf16,
    const float* __restrict__ Bm,
    const float* __restrict__ bias0, const float* __restrict__ bias1,
    float* __restrict__ C, int M, int N, int K)
{
  __shared__ ushort As[128*72];   // pad 64->72 elems: frag reads 2-way (free)
  __shared__ ushort Bs[128*72];
  const int nt = blockIdx.x * 128, mt = blockIdx.y * 128;
  const int tid = threadIdx.x;
  const int wv = tid >> 6, ln = tid & 63;
  const int wm = wv & 1, wn = wv >> 1;          // 2x2 wave grid (64x64 each)
  const int lc = ln & 15, quad = ln >> 4;
  f32x4 acc[4][4] = {{{0.f,0.f,0.f,0.f}}};

  for (int s = 0; s < K; s += 64){
    __syncthreads();
    #pragma unroll
    for (int cc = 0; cc < 4; ++cc){
      int ch = tid*4 + cc;                 // 0..1023: row=ch>>3, chunk=ch&7
      int r = ch >> 3, c = ch & 7;
      int ar = mt + r;
      if (abf16){
        const ushort* ap = (const ushort*)A + (size_t)ar*lda + s + c*8;
        *(bf16x8*)&As[r*72 + c*8] = *(const bf16x8*)ap;
      } else {
        const float* ap = A + (size_t)(rowmap ? rowmap[ar] : ar)*lda + s + c*8;
        float4 x = *(const float4*)ap, y = *(const float4*)(ap+4);
        *(bf16x8*)&As[r*72 + c*8] = cvt8(x, y);
      }
      int br = nt + r; if (br >= N) br = N - 1;
      const float* bp = Bm + (size_t)br*K + s + c*8;
      float4 bx = *(const float4*)bp, by = *(const float4*)(bp+4);
      *(bf16x8*)&Bs[r*72 + c*8] = cvt8(bx, by);
    }
    __syncthreads();
    #pragma unroll
    for (int kq = 0; kq < 2; ++kq){
      int cq = kq*4 + quad;
      bf16x8 af[4], bfv[4];
      #pragma unroll
      for (int i=0;i<4;i++) af[i]  = *(const bf16x8*)&As[(wm*64 + i*16 + lc)*72 + cq*8];
      #pragma unroll
      for (int j=0;j<4;j++) bfv[j] = *(const bf16x8*)&Bs[(wn*64 + j*16 + lc)*72 + cq*8];
      #pragma unroll
      for (int i=0;i<4;i++)
        #pragma unroll
        for (int j=0;j<4;j++)
          acc[i][j] = __builtin_amdgcn_mfma_f32_16x16x32_bf16(af[i], bfv[j], acc[i][j], 0, 0, 0);
    }
  }
  #pragma unroll
  for (int j=0;j<4;j++){
    int col = nt + wn*64 + j*16 + lc;
    if (col < N){
      float badd = (bias0 ? bias0[col] : 0.f) + (bias1 ? bias1[col] : 0.f);
      #pragma unroll
      for (int i=0;i<4;i++){
        int row = mt + wm*64 + i*16 + quad*4;
        #pragma unroll
        for (int r=0;r<4;r++)
          C[(size_t)(row+r)*N + col] = acc[i][j][r] + badd;
      }
    }
  }
}

// ---------------- fused 2-layer pipelined persistent RNN recurrence ----------------
// EXACT R6/R8 protocol (proven, 999us). Two deltas this round, both low-risk:
//   (1) pipelined poll: tid<8 keep TWO independent loads of their sub-counter
//       line in flight; exit still requires an OLDER sample >= tv, so the
//       safety argument is unchanged (detect lag ~RTT/2 instead of ~RTT).
//   (2) h2out stored as bf16 (the packbf is already computed for the protocol
//       store) -> downstream GEMM stages A with a plain copy.
__global__ __launch_bounds__(256, 1) void k_rnn_fused(
    const float* __restrict__ pre0, ushort* __restrict__ h2out,
    const float* __restrict__ w0hh, const float* __restrict__ w1ih,
    const float* __restrict__ w1hh,
    const float* __restrict__ b1ih, const float* __restrict__ b1hh,
    const ushort* __restrict__ hb0, ushort* __restrict__ hx, int* flags)
{
  __shared__ ushort w0F[16384], wiF[16384], whF[16384];  // frag-order weight slices
  __shared__ float red[4352];                            // [2 sets][wv][row 0..31][17]
  const int wg  = blockIdx.x;
  const int tid = threadIdx.x;
  const int j0  = wg * 16;
  int* ctr = flags + (wg & 7) * 32;           // 128B-strided sub-counter

  // stage the three 16x1024 weight slices as bf16 in MFMA fragment order
  for (int c = tid; c < 4096; c += 256){
    int rr = c >> 8, cc = (c & 255) * 4;
    int dst = ((cc >> 3)*16 + rr)*8 + (cc & 7);
    size_t srow = (size_t)(j0 + rr)*HH + cc;
    float4 w4; uint2 p;
    w4 = *(const float4*)&w0hh[srow];
    p.x = packbf(w4.x, w4.y); p.y = packbf(w4.z, w4.w);
    *(uint2*)&w0F[dst] = p;
    w4 = *(const float4*)&w1ih[srow];
    p.x = packbf(w4.x, w4.y); p.y = packbf(w4.z, w4.w);
    *(uint2*)&wiF[dst] = p;
    w4 = *(const float4*)&w1hh[srow];
    p.x = packbf(w4.x, w4.y); p.y = packbf(w4.z, w4.w);
    *(uint2*)&whF[dst] = p;
  }
  const int lane = tid & 63, wv = tid >> 6;
  const int col = lane & 15, quad = lane >> 4;
  const int ob = tid >> 3, oj = (tid << 1) & 15;

  float2 pre = *(const float2*)&pre0[((size_t)ob*SS + 0)*HH + j0 + oj];
  float2 pre2;
  pre2.x = b1ih[j0+oj]   + b1hh[j0+oj];
  pre2.y = b1ih[j0+oj+1] + b1hh[j0+oj+1];
  __syncthreads();

  for (int r = 0; r < SS; ++r){
    // h1[r-1] fragments (shared by both layer updates)
    const u64* s1 = (const u64*)(r == 0 ? hb0 : hx + ((r-1)&1)*32768);
    const u64* s2 = (r == 0) ? (const u64*)hb0
                  : (const u64*)(r == 1 ? hb0 + 32768 : hx + (2 + (r&1))*32768);
    f32x4 a0r[8], a1r[8], c0r[8], c1r[8];
    #pragma unroll
    for (int ks = 0; ks < 8; ++ks){
      int kb = wv*32 + ks*4 + quad;
      const u64* p = s1 + (kb << 6) + (col << 1);
      GLD(a0r[ks], p);
      GLD(a1r[ks], p + 32);
    }
    if (r > 0){
      #pragma unroll
      for (int ks = 0; ks < 8; ++ks){
        int kb = wv*32 + ks*4 + quad;
        const u64* p = s2 + (kb << 6) + (col << 1);
        GLD(c0r[ks], p);
        GLD(c1r[ks], p + 32);
      }
    }
    asm volatile("s_waitcnt vmcnt(0)" ::: "memory");
    __builtin_amdgcn_sched_barrier(0);

    f32x4 accA0 = {0.f,0.f,0.f,0.f}, accA1 = {0.f,0.f,0.f,0.f};
    f32x4 accB0 = {0.f,0.f,0.f,0.f}, accB1 = {0.f,0.f,0.f,0.f};
    #pragma unroll
    for (int ks = 0; ks < 8; ++ks){
      int kb = wv*32 + ks*4 + quad;
      bf16x8 b0 = *(const bf16x8*)&w0F[(kb*16 + col)*8];
      accA0 = __builtin_amdgcn_mfma_f32_16x16x32_bf16(asbf(a0r[ks]), b0, accA0, 0, 0, 0);
      accA1 = __builtin_amdgcn_mfma_f32_16x16x32_bf16(asbf(a1r[ks]), b0, accA1, 0, 0, 0);
      bf16x8 bi = *(const bf16x8*)&wiF[(kb*16 + col)*8];
      accB0 = __builtin_amdgcn_mfma_f32_16x16x32_bf16(asbf(a0r[ks]), bi, accB0, 0, 0, 0);
      accB1 = __builtin_amdgcn_mfma_f32_16x16x32_bf16(asbf(a1r[ks]), bi, accB1, 0, 0, 0);
    }
    if (r > 0){
      #pragma unroll
      for (int ks = 0; ks < 8; ++ks){
        int kb = wv*32 + ks*4 + quad;
        bf16x8 bh = *(const bf16x8*)&whF[(kb*16 + col)*8];
        accB0 = __builtin_amdgcn_mfma_f32_16x16x32_bf16(asbf(c0r[ks]), bh, accB0, 0, 0, 0);
        accB1 = __builtin_amdgcn_mfma_f32_16x16x32_bf16(asbf(c1r[ks]), bh, accB1, 0, 0, 0);
      }
    }
    #pragma unroll
    for (int q = 0; q < 4; ++q){
      red[wv*544 + (quad*4 + q)*17 + col]             = accA0[q];
      red[wv*544 + (16 + quad*4 + q)*17 + col]        = accA1[q];
      red[2176 + wv*544 + (quad*4 + q)*17 + col]      = accB0[q];
      red[2176 + wv*544 + (16 + quad*4 + q)*17 + col] = accB1[q];
    }
    __syncthreads();

    int ro = ob*17 + oj;
    float s0 = red[ro]   + red[544 + ro]   + red[1088 + ro]   + red[1632 + ro];
    float s1v= red[ro+1] + red[544 + ro+1] + red[1088 + ro+1] + red[1632 + ro+1];
    float v0 = ftanh(pre.x + s0);
    float v1 = ftanh(pre.y + s1v);
    int k = j0 + oj;
    unsigned off = ((unsigned)(k >> 3) << 7) + ((unsigned)ob << 2) + ((unsigned)(k & 7) >> 1);
    __hip_atomic_store((unsigned*)(hx + (r&1)*32768) + off, packbf(v0, v1),
                       __ATOMIC_RELAXED, __HIP_MEMORY_SCOPE_AGENT);
    unsigned pk2 = 0;
    if (r > 0){
      float s2v = red[2176+ro]   + red[2720+ro]   + red[3264+ro]   + red[3808+ro];
      float s3v = red[2176+ro+1] + red[2720+ro+1] + red[3264+ro+1] + red[3808+ro+1];
      pk2 = packbf(ftanh(pre2.x + s2v), ftanh(pre2.y + s3v));
      __hip_atomic_store((unsigned*)(hx + (2 + ((r-1)&1))*32768) + off, pk2,
                         __ATOMIC_RELAXED, __HIP_MEMORY_SCOPE_AGENT);
    }
    // all 256 threads' protocol stores durable at LLC, then ONE bump per wg
    asm volatile("s_waitcnt vmcnt(0)" ::: "memory");
    __syncthreads();
    if (tid == 0)
      __hip_atomic_fetch_add(ctr, 1, __ATOMIC_RELAXED, __HIP_MEMORY_SCOPE_AGENT);

    // off-protocol (cached): bf16 h2 for later GEMM + next pre0 prefetch
    if (r > 0)
      *((unsigned*)h2out + (((size_t)ob*SS + (r-1))*HH + j0 + oj) / 2) = pk2;
    int tn = (r + 1 < SS) ? r + 1 : SS - 1;
    pre = *(const float2*)&pre0[((size_t)ob*SS + tn)*HH + j0 + oj];

    // lanes 0..7 poll the 8 sub-counter lines; two independent loads in
    // flight so detect lag ~ RTT/2. Exit uses the OLDER sample (va).
    if (tid < 8){
      int tv = 8 * (r + 1);
      const int* fp = flags + tid*32;
      int va = __hip_atomic_load(fp, __ATOMIC_RELAXED, __HIP_MEMORY_SCOPE_AGENT);
      int vb = __hip_atomic_load(fp, __ATOMIC_RELAXED, __HIP_MEMORY_SCOPE_AGENT);
      while (va < tv){
        va = vb;
        vb = __hip_atomic_load(fp, __ATOMIC_RELAXED, __HIP_MEMORY_SCOPE_AGENT);
      }
    }
    __syncthreads();
  }

  // epilogue: h2[255] = tanh(b1 + h1[255] @ W1ih^T + h2[254] @ W1hh^T)
  {
    const u64* s1 = (const u64*)(hx + 32768);       // h1[255] (parity 1)
    const u64* s2 = (const u64*)(hx + 2*32768);     // h2[254] (parity 0)
    f32x4 a0r[8], a1r[8], c0r[8], c1r[8];
    #pragma unroll
    for (int ks = 0; ks < 8; ++ks){
      int kb = wv*32 + ks*4 + quad;
      const u64* p1 = s1 + (kb << 6) + (col << 1);
      GLD(a0r[ks], p1); GLD(a1r[ks], p1 + 32);
      const u64* p2 = s2 + (kb << 6) + (col << 1);
      GLD(c0r[ks], p2); GLD(c1r[ks], p2 + 32);
    }
    asm volatile("s_waitcnt vmcnt(0)" ::: "memory");
    __builtin_amdgcn_sched_barrier(0);
    f32x4 accB0 = {0.f,0.f,0.f,0.f}, accB1 = {0.f,0.f,0.f,0.f};
    #pragma unroll
    for (int ks = 0; ks < 8; ++ks){
      int kb = wv*32 + ks*4 + quad;
      bf16x8 bi = *(const bf16x8*)&wiF[(kb*16 + col)*8];
      accB0 = __builtin_amdgcn_mfma_f32_16x16x32_bf16(asbf(a0r[ks]), bi, accB0, 0, 0, 0);
      accB1 = __builtin_amdgcn_mfma_f32_16x16x32_bf16(asbf(a1r[ks]), bi, accB1, 0, 0, 0);
      bf16x8 bh = *(const bf16x8*)&whF[(kb*16 + col)*8];
      accB0 = __builtin_amdgcn_mfma_f32_16x16x32_bf16(asbf(c0r[ks]), bh, accB0, 0, 0, 0);
      accB1 = __builtin_amdgcn_mfma_f32_16x16x32_bf16(asbf(c1r[ks]), bh, accB1, 0, 0, 0);
    }
    #pragma unroll
    for (int q = 0; q < 4; ++q){
      red[wv*544 + (quad*4 + q)*17 + col]      = accB0[q];
      red[wv*544 + (16 + quad*4 + q)*17 + col] = accB1[q];
    }
    __syncthreads();
    int ro = ob*17 + oj;
    float s2v = red[ro]   + red[544 + ro]   + red[1088 + ro]   + red[1632 + ro];
    float s3v = red[ro+1] + red[544 + ro+1] + red[1088 + ro+1] + red[1632 + ro+1];
    *((unsigned*)h2out + (((size_t)ob*SS + (SS-1))*HH + j0 + oj) / 2) =
        packbf(ftanh(pre2.x + s2v), ftanh(pre2.y + s3v));
  }
}

// ---------------- cluster logsumexp over the BINNED row list (8 rows/wave) ----
__global__ __launch_bounds__(256) void k_cluster(
    const float* __restrict__ combo, int off, int ld, int Kp,
    const float* __restrict__ W, int Nc,
    const int* __restrict__ rowlist, const int* __restrict__ cntp, int ci,
    float* __restrict__ stats)
{
  __shared__ float ps[4][8][256];
  int lane = threadIdx.x & 63;
  int wvl  = threadIdx.x >> 6;
  int n0 = (blockIdx.x*4 + wvl) * 8;
  int count = cntp[ci];
  int rows[8];
  #pragma unroll
  for (int r=0;r<8;r++){
    rows[r] = (n0 + r < count) ? rowlist[n0 + r] : -1;
    if (rows[r] >= 0)
      for (int k=lane;k<Kp;k+=64)
        ps[wvl][r][k] = combo[(size_t)rows[r]*ld + off + k];
  }
  __syncthreads();
  if (rows[0] < 0) return;          // list is compact: all 8 invalid together

  float mx[8], sm[8];
  #pragma unroll
  for (int r=0;r<8;r++){ mx[r]=-1e30f; sm[r]=0.f; }
  for (int n=lane; n<Nc; n+=64){
    const float* wr = W + (size_t)n*Kp;
    float l[8]={0.f,0.f,0.f,0.f,0.f,0.f,0.f,0.f};
    for (int k=0;k<Kp;k+=4){
      float4 w4 = *(const float4*)(wr+k);
      #pragma unroll
      for (int r=0;r<8;r++){
        l[r] += w4.x*ps[wvl][r][k] + w4.y*ps[wvl][r][k+1]
              + w4.z*ps[wvl][r][k+2] + w4.w*ps[wvl][r][k+3];
      }
    }
    #pragma unroll
    for (int r=0;r<8;r++){
      float nm = fmaxf(mx[r], l[r]);
      sm[r] = sm[r]*__expf(mx[r]-nm) + __expf(l[r]-nm);
      mx[r] = nm;
    }
  }
  #pragma unroll
  for (int r=0;r<8;r++){
    for (int off2=32; off2; off2>>=1){
      float om = __shfl_down(mx[r], off2);
      float os = __shfl_down(sm[r], off2);
      float nm = fmaxf(mx[r], om);
      sm[r] = sm[r]*__expf(mx[r]-nm) + os*__expf(om-nm);
      mx[r] = nm;
    }
    if (lane==0 && rows[r] >= 0){
      stats[(size_t)rows[r]*6 + ci*2 + 0] = mx[r];
      stats[(size_t)rows[r]*6 + ci*2 + 1] = sm[r];
    }
  }
}

// ---------------- target logit for tail clusters (one wave per row) ----------------
__global__ __launch_bounds__(256) void k_tlogit(
    const int* __restrict__ tgtmap, const float* __restrict__ combo,
    const float* __restrict__ w0, const float* __restrict__ w1, const float* __restrict__ w2,
    float* __restrict__ tlogit)
{
  int lane = threadIdx.x & 63;
  int row = (blockIdx.x * 256 + threadIdx.x) >> 6;
  int tgt = tgtmap[row];
  float acc = 0.f;
  const float* pr = nullptr; const float* wr = nullptr; int Kp = 0;
  const float* crow = combo + (size_t)row*384;
  if      (tgt >= 1000){ pr = crow + 353; wr = w2 + (size_t)(tgt-1000)*16;  Kp=16;  }
  else if (tgt >= 100) { pr = crow + 289; wr = w1 + (size_t)(tgt-100)*64;   Kp=64;  }
  else if (tgt >= 30)  { pr = crow + 33;  wr = w0 + (size_t)(tgt-30)*256;   Kp=256; }
  for (int k=lane; k<Kp; k+=64) acc += pr[k]*wr[k];
  for (int off=32; off; off>>=1) acc += __shfl_down(acc, off);
  if (lane==0) tlogit[row] = acc;
}

// ---------------- final: head LSE + assemble NLL, reduce ----------------
__global__ __launch_bounds__(256) void k_final(
    const float* __restrict__ combo, const float* __restrict__ stats,
    const float* __restrict__ tlogit, const int* __restrict__ tgtmap,
    float* __restrict__ out)
{
  int row = blockIdx.x*256 + threadIdx.x;
  int tgt = tgtmap[row];
  float nll = 0.f;
  if (tgt != 0){
    const float* hrow = combo + (size_t)row*384;
    float m = hrow[0];
    #pragma unroll
    for (int i=1;i<33;i++) m = fmaxf(m, hrow[i]);
    float s = 0.f;
    #pragma unroll
    for (int i=0;i<33;i++) s += __expf(hrow[i]-m);
    float lse = __logf(s) + m;
    int ci = (tgt>=1000) ? 2 : (tgt>=100) ? 1 : (tgt>=30) ? 0 : -1;
    if (ci < 0){
      nll = lse - hrow[tgt];
    } else {
      float cm = stats[(size_t)row*6 + ci*2 + 0];
      float cs = stats[(size_t)row*6 + ci*2 + 1];
      nll = lse - hrow[30+ci] + (__logf(cs) + cm - tlogit[row]);
    }
  }
  float v = nll;
  for (int off=32; off; off>>=1) v += __shfl_down(v, off);
  __shared__ float wsum[4];
  int lane = threadIdx.x & 63, wv = threadIdx.x >> 6;
  if (lane==0) wsum[wv] = v;
  __syncthreads();
  if (threadIdx.x==0) atomicAdd(out, wsum[0]+wsum[1]+wsum[2]+wsum[3]);
}

extern "C" void kernel_launch(void* const* d_in, const int* in_sizes, int n_in,
                              void* d_out, int out_size, void* d_ws, size_t ws_size,
                              hipStream_t stream)
{
  const float* z      = (const float*)d_in[0];
  const float* emb    = (const float*)d_in[1];
  const float* l2h_w  = (const float*)d_in[2];
  const float* l2h_b  = (const float*)d_in[3];
  const float* w0ih   = (const float*)d_in[4];
  const float* w0hh   = (const float*)d_in[5];
  const float* b0ih   = (const float*)d_in[6];
  const float* b0hh   = (const float*)d_in[7];
  const float* w1ih   = (const float*)d_in[8];
  const float* w1hh   = (const float*)d_in[9];
  const float* b1ih   = (const float*)d_in[10];
  const float* b1hh   = (const float*)d_in[11];
  const float* head_w = (const float*)d_in[12];
  const float* p0     = (const float*)d_in[13];
  const float* tw0    = (const float*)d_in[14];
  const float* p1     = (const float*)d_in[15];
  const float* tw1    = (const float*)d_in[16];
  const float* p2     = (const float*)d_in[17];
  const float* tw2    = (const float*)d_in[18];
  const int* inp_seq  = (const int*)d_in[19];
  const int* tgt_seq  = (const int*)d_in[20];
  const int* length   = (const int*)d_in[21];

  float* ws   = (float*)d_ws;
  ushort* hb0 = (ushort*)ws;                      // 65536 ushorts (2 layers initial)
  ushort* hx  = hb0 + 65536;                      // 131072 ushorts: h1 ping/pong, h2 ping/pong
  float* bufA = ws + 98304;                       // 8192*1024 fp32 (pre0; later combo etc.)
  ushort* hbB = (ushort*)(bufA + (size_t)NROW*HH); // 8192*1024 bf16 (h2)
  int*   ibuf = (int*)(hbB + (size_t)NROW*HH);
  int* sorted_idx = ibuf;                         // 32
  int* tokmap = ibuf + 32;                        // 8192
  int* tgtmap = tokmap + NROW;                    // 8192
  int* flags  = tgtmap + NROW;                    // 512 ints: 8 sub-counters @128B
  int* bincnt = flags + 512;                      // 3 (+pad to 32)
  int* blist0 = bincnt + 32;                      // 8192
  int* blist1 = blist0 + NROW;                    // 8192
  int* blist2 = blist1 + NROW;                    // 8192
  float* combo = bufA;                            // 8192*384 (head 0..32 | p0 33..288 | p1 289..352 | p2 353..368)
  float* stats = bufA + (size_t)NROW*384;         // 8192*6
  float* tlog  = stats + (size_t)NROW*6;          // 8192
  float* wcat  = tlog + NROW;                     // 384*1024

  float* outF = (float*)d_out;
  hipMemsetAsync(outF, 0, sizeof(float), stream);
  hipMemsetAsync(flags, 0, 544*sizeof(int), stream);

  k_sort<<<1, 32, 0, stream>>>(length, sorted_idx);
  k_maps<<<32, 256, 0, stream>>>(sorted_idx, inp_seq, tgt_seq, tokmap, tgtmap);
  k_hid<<<256, 256, 0, stream>>>(z, l2h_w, l2h_b, hb0);
  k_bin<<<32, 256, 0, stream>>>(tgtmap, bincnt, blist0, blist1, blist2);

  // pre0 = emb[tok] @ w0ih^T + b0ih + b0hh   (bf16 MFMA, A gathered fp32)
  k_gemm_bf16<<<dim3(HH/128, NROW/128), 256, 0, stream>>>(emb, EE, tokmap, 0, w0ih,
                                                          b0ih, b0hh, bufA, NROW, HH, EE);
  // fused 2-layer pipelined recurrence: hbB := h2 (bf16; W1ih applied in-kernel)
  k_rnn_fused<<<NWG, 256, 0, stream>>>(bufA, hbB, w0hh, w1ih, w1hh, b1ih, b1hh,
                                       hb0, hx, flags);

  // single fused output GEMM: combo = h2 @ [head;p0;p1;p2]^T (A already bf16)
  k_wcat<<<384, 256, 0, stream>>>(head_w, p0, p1, p2, wcat);
  k_gemm_bf16<<<dim3(3, NROW/128), 256, 0, stream>>>((const float*)hbB, HH, nullptr, 1,
                                                     wcat, nullptr, nullptr,
                                                     combo, NROW, 384, HH);

  // cluster LSE only for rows whose TARGET is in that cluster (binned lists)
  k_cluster<<<NROW/32, 256, 0, stream>>>(combo, 33,  384, 256, tw0, 70,
                                         blist0, bincnt, 0, stats);
  k_cluster<<<NROW/32, 256, 0, stream>>>(combo, 289, 384, 64,  tw1, 900,
                                         blist1, bincnt, 1, stats);
  k_cluster<<<NROW/32, 256, 0, stream>>>(combo, 353, 384, 16,  tw2, 19000,
                                         blist2, bincnt, 2, stats);
  k_tlogit<<<NROW/4, 256, 0, stream>>>(tgtmap, combo, tw0, tw1, tw2, tlog);
  k_final<<<NROW/256, 256, 0, stream>>>(combo, stats, tlog, tgtmap, outF);
}

// Round 10
// 1528.614 us; speedup vs baseline: 1.0989x; 1.0989x over previous
//
#include <hip/hip_runtime.h>
#include <hip/hip_bf16.h>
#include <math.h>

#define BB 32
#define SS 256
#define EE 512
#define HH 1024
#define LDM 256
#define NROW (BB*SS)   // 8192
#define NWG 64         // cooperative wgs for recurrence (1 per 4 CUs; all resident)

typedef __attribute__((ext_vector_type(8))) short bf16x8;
typedef __attribute__((ext_vector_type(4))) float f32x4;
typedef unsigned long long u64;

static __device__ inline unsigned short f2bf(float f){
  unsigned u = __float_as_uint(f);
  unsigned r = (u + 0x7fffu + ((u >> 16) & 1u)) >> 16;
  return (unsigned short)r;
}
// cheap round (no tie-to-even) for GEMM staging
static __device__ inline unsigned short f2bf_fast(float f){
  return (unsigned short)((__float_as_uint(f) + 0x8000u) >> 16);
}
static __device__ inline bf16x8 cvt8(float4 x, float4 y){
  union { ushort s[8]; bf16x8 v; } t;
  t.s[0]=f2bf_fast(x.x); t.s[1]=f2bf_fast(x.y); t.s[2]=f2bf_fast(x.z); t.s[3]=f2bf_fast(x.w);
  t.s[4]=f2bf_fast(y.x); t.s[5]=f2bf_fast(y.y); t.s[6]=f2bf_fast(y.z); t.s[7]=f2bf_fast(y.w);
  return t.v;
}
static __device__ inline unsigned packbf(float a, float b){
  return (unsigned)f2bf(a) | ((unsigned)f2bf(b) << 16);
}

// fast tanh: 1 - 2/(e^{2x}+1)
static __device__ inline float ftanh(float x){
  float e = __expf(2.f*x);
  return 1.f - 2.f/(e + 1.f);
}

// coherent (L1/L2-bypass, LLC-read) 16B load on the NORMAL coalescing path.
// Result lands asynchronously: caller must s_waitcnt vmcnt(0) + sched_barrier
// before first use.
#define GLD(dst, p) asm volatile("global_load_dwordx4 %0, %1, off sc0 sc1" \
                                 : "=v"(dst) : "v"(p) : "memory")

static __device__ inline bf16x8 asbf(f32x4 x){
  union { f32x4 f; bf16x8 b; } u; u.f = x; return u.b;
}

// ---------------- sort (stable argsort by descending length) ----------------
__global__ void k_sort(const int* __restrict__ length, int* __restrict__ sorted_idx){
  int b = threadIdx.x;
  if (b >= BB) return;
  int lb = length[b];
  int r = 0;
  for (int o = 0; o < BB; ++o){
    int lo = length[o];
    if (lo > lb || (lo == lb && o < b)) ++r;
  }
  sorted_idx[r] = b;
}

// token / target maps in sorted order
__global__ void k_maps(const int* __restrict__ sorted_idx,
                       const int* __restrict__ inp_seq, const int* __restrict__ tgt_seq,
                       int* __restrict__ tokmap, int* __restrict__ tgtmap){
  int bs = blockIdx.x; int t = threadIdx.x;
  int b = sorted_idx[bs];
  tokmap[bs*SS + t] = inp_seq[b*SS + t];
  tgtmap[bs*SS + t] = tgt_seq[b*SS + t];
}

// hid = z @ l2h_w.T + l2h_b, written DIRECTLY in bf16 fragment-major layout
__global__ __launch_bounds__(256) void k_hid(const float* __restrict__ z,
        const float* __restrict__ w, const float* __restrict__ bias,
        ushort* __restrict__ hb0){
  int id = blockIdx.x*256 + threadIdx.x;      // flat [B,2H] index = b*2048 + c
  int b = id >> 11, c = id & 2047;
  const float4* zr = (const float4*)(z + b*LDM);
  const float4* wr = (const float4*)(w + (size_t)c*LDM);
  float a0=0,a1=0,a2=0,a3=0;
  #pragma unroll 4
  for (int k=0;k<LDM/4;k++){ float4 zz=zr[k], ww=wr[k];
    a0+=zz.x*ww.x; a1+=zz.y*ww.y; a2+=zz.z*ww.z; a3+=zz.w*ww.w; }
  float val = a0+a1+a2+a3 + bias[c];
  int layer = id >> 15, bp = (id >> 10) & 31, j = id & 1023;
  hb0[(layer<<15) + ((j>>3)<<8) + (bp<<3) + (j&7)] = f2bf(val);
}

// concat [head_w(33); p0(256); p1(64); p2(16); zeros(15)] -> wcat[384][1024]
__global__ __launch_bounds__(256) void k_wcat(
    const float* __restrict__ head_w, const float* __restrict__ p0,
    const float* __restrict__ p1, const float* __restrict__ p2,
    float* __restrict__ wcat){
  int row = blockIdx.x; int t = threadIdx.x;
  float4* dst = (float4*)(wcat + (size_t)row*HH);
  const float* src;
  if      (row < 33)  src = head_w + (size_t)row*HH;
  else if (row < 289) src = p0 + (size_t)(row-33)*HH;
  else if (row < 353) src = p1 + (size_t)(row-289)*HH;
  else if (row < 369) src = p2 + (size_t)(row-353)*HH;
  else { dst[t] = make_float4(0.f,0.f,0.f,0.f); return; }
  dst[t] = ((const float4*)src)[t];
}

// bucket unmasked rows by target cluster (ballot-aggregated atomics)
__global__ __launch_bounds__(256) void k_bin(
    const int* __restrict__ tgtmap, int* __restrict__ cnt,
    int* __restrict__ l0, int* __restrict__ l1, int* __restrict__ l2)
{
  int row = blockIdx.x*256 + threadIdx.x;
  int tgt = tgtmap[row];
  int ci = (tgt == 0) ? -1 : (tgt >= 1000) ? 2 : (tgt >= 100) ? 1 : (tgt >= 30) ? 0 : -1;
  int lane = threadIdx.x & 63;
  #pragma unroll
  for (int c = 0; c < 3; ++c){
    unsigned long long mask = __ballot(ci == c);
    int nc = __popcll(mask);
    int base = 0;
    if (lane == 0 && nc) base = atomicAdd(&cnt[c], nc);
    base = __shfl(base, 0);
    if (ci == c){
      int pos = __popcll(mask & ((1ull << lane) - 1ull));
      int* lst = (c == 0) ? l0 : (c == 1) ? l1 : l2;
      lst[base + pos] = row;
    }
  }
}

// ---------------- bf16 MFMA GEMM: C[M,N] = A[M,K] @ Bm[N,K]^T (+bias0+bias1)
// abf16: A is already bf16 (ushort, row-major, lda elems) -> staging is a copy.
__global__ __launch_bounds__(256) void k_gemm_bf16(
    const float* __restrict__ A, int lda, const int* __restrict__ rowmap, int abf16,
    const float* __restrict__ Bm,
    const float* __restrict__ bias0, const float* __restrict__ bias1,
    float* __restrict__ C, int M, int N, int K)
{
  __shared__ ushort As[128*72];   // pad 64->72 elems: frag reads 2-way (free)
  __shared__ ushort Bs[128*72];
  const int nt = blockIdx.x * 128, mt = blockIdx.y * 128;
  const int tid = threadIdx.x;
  const int wv = tid >> 6, ln = tid & 63;
  const int wm = wv & 1, wn = wv >> 1;          // 2x2 wave grid (64x64 each)
  const int lc = ln & 15, quad = ln >> 4;
  f32x4 acc[4][4] = {{{0.f,0.f,0.f,0.f}}};

  for (int s = 0; s < K; s += 64){
    __syncthreads();
    #pragma unroll
    for (int cc = 0; cc < 4; ++cc){
      int ch = tid*4 + cc;                 // 0..1023: row=ch>>3, chunk=ch&7
      int r = ch >> 3, c = ch & 7;
      int ar = mt + r;
      if (abf16){
        const ushort* ap = (const ushort*)A + (size_t)ar*lda + s + c*8;
        *(bf16x8*)&As[r*72 + c*8] = *(const bf16x8*)ap;
      } else {
        const float* ap = A + (size_t)(rowmap ? rowmap[ar] : ar)*lda + s + c*8;
        float4 x = *(const float4*)ap, y = *(const float4*)(ap+4);
        *(bf16x8*)&As[r*72 + c*8] = cvt8(x, y);
      }
      int br = nt + r; if (br >= N) br = N - 1;
      const float* bp = Bm + (size_t)br*K + s + c*8;
      float4 bx = *(const float4*)bp, by = *(const float4*)(bp+4);
      *(bf16x8*)&Bs[r*72 + c*8] = cvt8(bx, by);
    }
    __syncthreads();
    #pragma unroll
    for (int kq = 0; kq < 2; ++kq){
      int cq = kq*4 + quad;
      bf16x8 af[4], bfv[4];
      #pragma unroll
      for (int i=0;i<4;i++) af[i]  = *(const bf16x8*)&As[(wm*64 + i*16 + lc)*72 + cq*8];
      #pragma unroll
      for (int j=0;j<4;j++) bfv[j] = *(const bf16x8*)&Bs[(wn*64 + j*16 + lc)*72 + cq*8];
      #pragma unroll
      for (int i=0;i<4;i++)
        #pragma unroll
        for (int j=0;j<4;j++)
          acc[i][j] = __builtin_amdgcn_mfma_f32_16x16x32_bf16(af[i], bfv[j], acc[i][j], 0, 0, 0);
    }
  }
  #pragma unroll
  for (int j=0;j<4;j++){
    int col = nt + wn*64 + j*16 + lc;
    if (col < N){
      float badd = (bias0 ? bias0[col] : 0.f) + (bias1 ? bias1[col] : 0.f);
      #pragma unroll
      for (int i=0;i<4;i++){
        int row = mt + wm*64 + i*16 + quad*4;
        #pragma unroll
        for (int r=0;r<4;r++)
          C[(size_t)(row+r)*N + col] = acc[i][j][r] + badd;
      }
    }
  }
}

// ---------------- fused 2-layer pipelined persistent RNN recurrence ----------------
// EXACT R6/R8 protocol (proven, 999us): single phase per round, coalesced
// sc0/sc1 loads, ONE vmcnt(0)+sched_barrier before all MFMAs, weights from
// LDS, two h stores, WG drain+sync, tid0 bump to 8x 128B-strided sub-counter,
// tid<8 simple poll, sync. (R9's pipelined poll measured NEUTRAL -> reverted.)
// SINGLE delta vs R8: h2out stored as bf16 (pk2 already computed for the
// protocol store) -> downstream combo GEMM stages A with a plain 16B copy.
__global__ __launch_bounds__(256, 1) void k_rnn_fused(
    const float* __restrict__ pre0, ushort* __restrict__ h2out,
    const float* __restrict__ w0hh, const float* __restrict__ w1ih,
    const float* __restrict__ w1hh,
    const float* __restrict__ b1ih, const float* __restrict__ b1hh,
    const ushort* __restrict__ hb0, ushort* __restrict__ hx, int* flags)
{
  __shared__ ushort w0F[16384], wiF[16384], whF[16384];  // frag-order weight slices
  __shared__ float red[4352];                            // [2 sets][wv][row 0..31][17]
  const int wg  = blockIdx.x;
  const int tid = threadIdx.x;
  const int j0  = wg * 16;
  int* ctr = flags + (wg & 7) * 32;           // 128B-strided sub-counter

  // stage the three 16x1024 weight slices as bf16 in MFMA fragment order
  for (int c = tid; c < 4096; c += 256){
    int rr = c >> 8, cc = (c & 255) * 4;
    int dst = ((cc >> 3)*16 + rr)*8 + (cc & 7);
    size_t srow = (size_t)(j0 + rr)*HH + cc;
    float4 w4; uint2 p;
    w4 = *(const float4*)&w0hh[srow];
    p.x = packbf(w4.x, w4.y); p.y = packbf(w4.z, w4.w);
    *(uint2*)&w0F[dst] = p;
    w4 = *(const float4*)&w1ih[srow];
    p.x = packbf(w4.x, w4.y); p.y = packbf(w4.z, w4.w);
    *(uint2*)&wiF[dst] = p;
    w4 = *(const float4*)&w1hh[srow];
    p.x = packbf(w4.x, w4.y); p.y = packbf(w4.z, w4.w);
    *(uint2*)&whF[dst] = p;
  }
  const int lane = tid & 63, wv = tid >> 6;
  const int col = lane & 15, quad = lane >> 4;
  const int ob = tid >> 3, oj = (tid << 1) & 15;

  float2 pre = *(const float2*)&pre0[((size_t)ob*SS + 0)*HH + j0 + oj];
  float2 pre2;
  pre2.x = b1ih[j0+oj]   + b1hh[j0+oj];
  pre2.y = b1ih[j0+oj+1] + b1hh[j0+oj+1];
  __syncthreads();

  for (int r = 0; r < SS; ++r){
    // h1[r-1] fragments (shared by both layer updates)
    const u64* s1 = (const u64*)(r == 0 ? hb0 : hx + ((r-1)&1)*32768);
    const u64* s2 = (r == 0) ? (const u64*)hb0
                  : (const u64*)(r == 1 ? hb0 + 32768 : hx + (2 + (r&1))*32768);
    f32x4 a0r[8], a1r[8], c0r[8], c1r[8];
    #pragma unroll
    for (int ks = 0; ks < 8; ++ks){
      int kb = wv*32 + ks*4 + quad;
      const u64* p = s1 + (kb << 6) + (col << 1);
      GLD(a0r[ks], p);
      GLD(a1r[ks], p + 32);
    }
    if (r > 0){
      #pragma unroll
      for (int ks = 0; ks < 8; ++ks){
        int kb = wv*32 + ks*4 + quad;
        const u64* p = s2 + (kb << 6) + (col << 1);
        GLD(c0r[ks], p);
        GLD(c1r[ks], p + 32);
      }
    }
    asm volatile("s_waitcnt vmcnt(0)" ::: "memory");
    __builtin_amdgcn_sched_barrier(0);

    f32x4 accA0 = {0.f,0.f,0.f,0.f}, accA1 = {0.f,0.f,0.f,0.f};
    f32x4 accB0 = {0.f,0.f,0.f,0.f}, accB1 = {0.f,0.f,0.f,0.f};
    #pragma unroll
    for (int ks = 0; ks < 8; ++ks){
      int kb = wv*32 + ks*4 + quad;
      bf16x8 b0 = *(const bf16x8*)&w0F[(kb*16 + col)*8];
      accA0 = __builtin_amdgcn_mfma_f32_16x16x32_bf16(asbf(a0r[ks]), b0, accA0, 0, 0, 0);
      accA1 = __builtin_amdgcn_mfma_f32_16x16x32_bf16(asbf(a1r[ks]), b0, accA1, 0, 0, 0);
      bf16x8 bi = *(const bf16x8*)&wiF[(kb*16 + col)*8];
      accB0 = __builtin_amdgcn_mfma_f32_16x16x32_bf16(asbf(a0r[ks]), bi, accB0, 0, 0, 0);
      accB1 = __builtin_amdgcn_mfma_f32_16x16x32_bf16(asbf(a1r[ks]), bi, accB1, 0, 0, 0);
    }
    if (r > 0){
      #pragma unroll
      for (int ks = 0; ks < 8; ++ks){
        int kb = wv*32 + ks*4 + quad;
        bf16x8 bh = *(const bf16x8*)&whF[(kb*16 + col)*8];
        accB0 = __builtin_amdgcn_mfma_f32_16x16x32_bf16(asbf(c0r[ks]), bh, accB0, 0, 0, 0);
        accB1 = __builtin_amdgcn_mfma_f32_16x16x32_bf16(asbf(c1r[ks]), bh, accB1, 0, 0, 0);
      }
    }
    #pragma unroll
    for (int q = 0; q < 4; ++q){
      red[wv*544 + (quad*4 + q)*17 + col]             = accA0[q];
      red[wv*544 + (16 + quad*4 + q)*17 + col]        = accA1[q];
      red[2176 + wv*544 + (quad*4 + q)*17 + col]      = accB0[q];
      red[2176 + wv*544 + (16 + quad*4 + q)*17 + col] = accB1[q];
    }
    __syncthreads();

    int ro = ob*17 + oj;
    float s0 = red[ro]   + red[544 + ro]   + red[1088 + ro]   + red[1632 + ro];
    float s1v= red[ro+1] + red[544 + ro+1] + red[1088 + ro+1] + red[1632 + ro+1];
    float v0 = ftanh(pre.x + s0);
    float v1 = ftanh(pre.y + s1v);
    int k = j0 + oj;
    unsigned off = ((unsigned)(k >> 3) << 7) + ((unsigned)ob << 2) + ((unsigned)(k & 7) >> 1);
    __hip_atomic_store((unsigned*)(hx + (r&1)*32768) + off, packbf(v0, v1),
                       __ATOMIC_RELAXED, __HIP_MEMORY_SCOPE_AGENT);
    unsigned pk2 = 0;
    if (r > 0){
      float s2v = red[2176+ro]   + red[2720+ro]   + red[3264+ro]   + red[3808+ro];
      float s3v = red[2176+ro+1] + red[2720+ro+1] + red[3264+ro+1] + red[3808+ro+1];
      pk2 = packbf(ftanh(pre2.x + s2v), ftanh(pre2.y + s3v));
      __hip_atomic_store((unsigned*)(hx + (2 + ((r-1)&1))*32768) + off, pk2,
                         __ATOMIC_RELAXED, __HIP_MEMORY_SCOPE_AGENT);
    }
    // all 256 threads' protocol stores durable at LLC, then ONE bump per wg
    asm volatile("s_waitcnt vmcnt(0)" ::: "memory");
    __syncthreads();
    if (tid == 0)
      __hip_atomic_fetch_add(ctr, 1, __ATOMIC_RELAXED, __HIP_MEMORY_SCOPE_AGENT);

    // off-protocol (cached): bf16 h2 for later GEMM + next pre0 prefetch
    if (r > 0)
      *((unsigned*)h2out + (((size_t)ob*SS + (r-1))*HH + j0 + oj) / 2) = pk2;
    int tn = (r + 1 < SS) ? r + 1 : SS - 1;
    pre = *(const float2*)&pre0[((size_t)ob*SS + tn)*HH + j0 + oj];

    // lanes 0..7 poll the 8 sub-counter lines with ONE load instruction/iter
    if (tid < 8){
      int tv = 8 * (r + 1);
      while (__hip_atomic_load(flags + tid*32, __ATOMIC_RELAXED,
                               __HIP_MEMORY_SCOPE_AGENT) < tv) {}
    }
    __syncthreads();
  }

  // epilogue: h2[255] = tanh(b1 + h1[255] @ W1ih^T + h2[254] @ W1hh^T)
  {
    const u64* s1 = (const u64*)(hx + 32768);       // h1[255] (parity 1)
    const u64* s2 = (const u64*)(hx + 2*32768);     // h2[254] (parity 0)
    f32x4 a0r[8], a1r[8], c0r[8], c1r[8];
    #pragma unroll
    for (int ks = 0; ks < 8; ++ks){
      int kb = wv*32 + ks*4 + quad;
      const u64* p1 = s1 + (kb << 6) + (col << 1);
      GLD(a0r[ks], p1); GLD(a1r[ks], p1 + 32);
      const u64* p2 = s2 + (kb << 6) + (col << 1);
      GLD(c0r[ks], p2); GLD(c1r[ks], p2 + 32);
    }
    asm volatile("s_waitcnt vmcnt(0)" ::: "memory");
    __builtin_amdgcn_sched_barrier(0);
    f32x4 accB0 = {0.f,0.f,0.f,0.f}, accB1 = {0.f,0.f,0.f,0.f};
    #pragma unroll
    for (int ks = 0; ks < 8; ++ks){
      int kb = wv*32 + ks*4 + quad;
      bf16x8 bi = *(const bf16x8*)&wiF[(kb*16 + col)*8];
      accB0 = __builtin_amdgcn_mfma_f32_16x16x32_bf16(asbf(a0r[ks]), bi, accB0, 0, 0, 0);
      accB1 = __builtin_amdgcn_mfma_f32_16x16x32_bf16(asbf(a1r[ks]), bi, accB1, 0, 0, 0);
      bf16x8 bh = *(const bf16x8*)&whF[(kb*16 + col)*8];
      accB0 = __builtin_amdgcn_mfma_f32_16x16x32_bf16(asbf(c0r[ks]), bh, accB0, 0, 0, 0);
      accB1 = __builtin_amdgcn_mfma_f32_16x16x32_bf16(asbf(c1r[ks]), bh, accB1, 0, 0, 0);
    }
    #pragma unroll
    for (int q = 0; q < 4; ++q){
      red[wv*544 + (quad*4 + q)*17 + col]      = accB0[q];
      red[wv*544 + (16 + quad*4 + q)*17 + col] = accB1[q];
    }
    __syncthreads();
    int ro = ob*17 + oj;
    float s2v = red[ro]   + red[544 + ro]   + red[1088 + ro]   + red[1632 + ro];
    float s3v = red[ro+1] + red[544 + ro+1] + red[1088 + ro+1] + red[1632 + ro+1];
    *((unsigned*)h2out + (((size_t)ob*SS + (SS-1))*HH + j0 + oj) / 2) =
        packbf(ftanh(pre2.x + s2v), ftanh(pre2.y + s3v));
  }
}

// ---------------- cluster logsumexp over the BINNED row list (4 rows/wave, R8) ----
__global__ __launch_bounds__(256) void k_cluster(
    const float* __restrict__ combo, int off, int ld, int Kp,
    const float* __restrict__ W, int Nc,
    const int* __restrict__ rowlist, const int* __restrict__ cntp, int ci,
    float* __restrict__ stats)
{
  __shared__ float ps[4][4][256];
  int lane = threadIdx.x & 63;
  int wvl  = threadIdx.x >> 6;
  int n0 = (blockIdx.x*4 + wvl) * 4;
  int count = cntp[ci];
  int rows[4];
  #pragma unroll
  for (int r=0;r<4;r++){
    rows[r] = (n0 + r < count) ? rowlist[n0 + r] : -1;
    if (rows[r] >= 0)
      for (int k=lane;k<Kp;k+=64)
        ps[wvl][r][k] = combo[(size_t)rows[r]*ld + off + k];
  }
  __syncthreads();
  if (rows[0] < 0) return;          // list is compact: all 4 invalid together

  float mx[4], sm[4];
  #pragma unroll
  for (int r=0;r<4;r++){ mx[r]=-1e30f; sm[r]=0.f; }
  for (int n=lane; n<Nc; n+=64){
    const float* wr = W + (size_t)n*Kp;
    float l[4]={0.f,0.f,0.f,0.f};
    for (int k=0;k<Kp;k+=4){
      float4 w4 = *(const float4*)(wr+k);
      #pragma unroll
      for (int r=0;r<4;r++){
        l[r] += w4.x*ps[wvl][r][k] + w4.y*ps[wvl][r][k+1]
              + w4.z*ps[wvl][r][k+2] + w4.w*ps[wvl][r][k+3];
      }
    }
    #pragma unroll
    for (int r=0;r<4;r++){
      float nm = fmaxf(mx[r], l[r]);
      sm[r] = sm[r]*__expf(mx[r]-nm) + __expf(l[r]-nm);
      mx[r] = nm;
    }
  }
  #pragma unroll
  for (int r=0;r<4;r++){
    for (int off2=32; off2; off2>>=1){
      float om = __shfl_down(mx[r], off2);
      float os = __shfl_down(sm[r], off2);
      float nm = fmaxf(mx[r], om);
      sm[r] = sm[r]*__expf(mx[r]-nm) + os*__expf(om-nm);
      mx[r] = nm;
    }
    if (lane==0 && rows[r] >= 0){
      stats[(size_t)rows[r]*6 + ci*2 + 0] = mx[r];
      stats[(size_t)rows[r]*6 + ci*2 + 1] = sm[r];
    }
  }
}

// ---------------- target logit for tail clusters (one wave per row) ----------------
__global__ __launch_bounds__(256) void k_tlogit(
    const int* __restrict__ tgtmap, const float* __restrict__ combo,
    const float* __restrict__ w0, const float* __restrict__ w1, const float* __restrict__ w2,
    float* __restrict__ tlogit)
{
  int lane = threadIdx.x & 63;
  int row = (blockIdx.x * 256 + threadIdx.x) >> 6;
  int tgt = tgtmap[row];
  float acc = 0.f;
  const float* pr = nullptr; const float* wr = nullptr; int Kp = 0;
  const float* crow = combo + (size_t)row*384;
  if      (tgt >= 1000){ pr = crow + 353; wr = w2 + (size_t)(tgt-1000)*16;  Kp=16;  }
  else if (tgt >= 100) { pr = crow + 289; wr = w1 + (size_t)(tgt-100)*64;   Kp=64;  }
  else if (tgt >= 30)  { pr = crow + 33;  wr = w0 + (size_t)(tgt-30)*256;   Kp=256; }
  for (int k=lane; k<Kp; k+=64) acc += pr[k]*wr[k];
  for (int off=32; off; off>>=1) acc += __shfl_down(acc, off);
  if (lane==0) tlogit[row] = acc;
}

// ---------------- final: head LSE + assemble NLL, reduce ----------------
__global__ __launch_bounds__(256) void k_final(
    const float* __restrict__ combo, const float* __restrict__ stats,
    const float* __restrict__ tlogit, const int* __restrict__ tgtmap,
    float* __restrict__ out)
{
  int row = blockIdx.x*256 + threadIdx.x;
  int tgt = tgtmap[row];
  float nll = 0.f;
  if (tgt != 0){
    const float* hrow = combo + (size_t)row*384;
    float m = hrow[0];
    #pragma unroll
    for (int i=1;i<33;i++) m = fmaxf(m, hrow[i]);
    float s = 0.f;
    #pragma unroll
    for (int i=0;i<33;i++) s += __expf(hrow[i]-m);
    float lse = __logf(s) + m;
    int ci = (tgt>=1000) ? 2 : (tgt>=100) ? 1 : (tgt>=30) ? 0 : -1;
    if (ci < 0){
      nll = lse - hrow[tgt];
    } else {
      float cm = stats[(size_t)row*6 + ci*2 + 0];
      float cs = stats[(size_t)row*6 + ci*2 + 1];
      nll = lse - hrow[30+ci] + (__logf(cs) + cm - tlogit[row]);
    }
  }
  float v = nll;
  for (int off=32; off; off>>=1) v += __shfl_down(v, off);
  __shared__ float wsum[4];
  int lane = threadIdx.x & 63, wv = threadIdx.x >> 6;
  if (lane==0) wsum[wv] = v;
  __syncthreads();
  if (threadIdx.x==0) atomicAdd(out, wsum[0]+wsum[1]+wsum[2]+wsum[3]);
}

extern "C" void kernel_launch(void* const* d_in, const int* in_sizes, int n_in,
                              void* d_out, int out_size, void* d_ws, size_t ws_size,
                              hipStream_t stream)
{
  const float* z      = (const float*)d_in[0];
  const float* emb    = (const float*)d_in[1];
  const float* l2h_w  = (const float*)d_in[2];
  const float* l2h_b  = (const float*)d_in[3];
  const float* w0ih   = (const float*)d_in[4];
  const float* w0hh   = (const float*)d_in[5];
  const float* b0ih   = (const float*)d_in[6];
  const float* b0hh   = (const float*)d_in[7];
  const float* w1ih   = (const float*)d_in[8];
  const float* w1hh   = (const float*)d_in[9];
  const float* b1ih   = (const float*)d_in[10];
  const float* b1hh   = (const float*)d_in[11];
  const float* head_w = (const float*)d_in[12];
  const float* p0     = (const float*)d_in[13];
  const float* tw0    = (const float*)d_in[14];
  const float* p1     = (const float*)d_in[15];
  const float* tw1    = (const float*)d_in[16];
  const float* p2     = (const float*)d_in[17];
  const float* tw2    = (const float*)d_in[18];
  const int* inp_seq  = (const int*)d_in[19];
  const int* tgt_seq  = (const int*)d_in[20];
  const int* length   = (const int*)d_in[21];

  float* ws   = (float*)d_ws;
  ushort* hb0 = (ushort*)ws;                      // 65536 ushorts (2 layers initial)
  ushort* hx  = hb0 + 65536;                      // 131072 ushorts: h1 ping/pong, h2 ping/pong
  float* bufA = ws + 98304;                       // 8192*1024 fp32 (pre0; later combo etc.)
  ushort* hbB = (ushort*)(bufA + (size_t)NROW*HH); // 8192*1024 bf16 (h2)
  int*   ibuf = (int*)(hbB + (size_t)NROW*HH);
  int* sorted_idx = ibuf;                         // 32
  int* tokmap = ibuf + 32;                        // 8192
  int* tgtmap = tokmap + NROW;                    // 8192
  int* flags  = tgtmap + NROW;                    // 512 ints: 8 sub-counters @128B
  int* bincnt = flags + 512;                      // 3 (+pad to 32)
  int* blist0 = bincnt + 32;                      // 8192
  int* blist1 = blist0 + NROW;                    // 8192
  int* blist2 = blist1 + NROW;                    // 8192
  float* combo = bufA;                            // 8192*384 (head 0..32 | p0 33..288 | p1 289..352 | p2 353..368)
  float* stats = bufA + (size_t)NROW*384;         // 8192*6
  float* tlog  = stats + (size_t)NROW*6;          // 8192
  float* wcat  = tlog + NROW;                     // 384*1024

  float* outF = (float*)d_out;
  hipMemsetAsync(outF, 0, sizeof(float), stream);
  hipMemsetAsync(flags, 0, 544*sizeof(int), stream);

  k_sort<<<1, 32, 0, stream>>>(length, sorted_idx);
  k_maps<<<32, 256, 0, stream>>>(sorted_idx, inp_seq, tgt_seq, tokmap, tgtmap);
  k_hid<<<256, 256, 0, stream>>>(z, l2h_w, l2h_b, hb0);
  k_bin<<<32, 256, 0, stream>>>(tgtmap, bincnt, blist0, blist1, blist2);

  // pre0 = emb[tok] @ w0ih^T + b0ih + b0hh   (bf16 MFMA, A gathered fp32)
  k_gemm_bf16<<<dim3(HH/128, NROW/128), 256, 0, stream>>>(emb, EE, tokmap, 0, w0ih,
                                                          b0ih, b0hh, bufA, NROW, HH, EE);
  // fused 2-layer pipelined recurrence: hbB := h2 (bf16; W1ih applied in-kernel)
  k_rnn_fused<<<NWG, 256, 0, stream>>>(bufA, hbB, w0hh, w1ih, w1hh, b1ih, b1hh,
                                       hb0, hx, flags);

  // single fused output GEMM: combo = h2 @ [head;p0;p1;p2]^T (A already bf16)
  k_wcat<<<384, 256, 0, stream>>>(head_w, p0, p1, p2, wcat);
  k_gemm_bf16<<<dim3(3, NROW/128), 256, 0, stream>>>((const float*)hbB, HH, nullptr, 1,
                                                     wcat, nullptr, nullptr,
                                                     combo, NROW, 384, HH);

  // cluster LSE only for rows whose TARGET is in that cluster (binned lists)
  k_cluster<<<NROW/16, 256, 0, stream>>>(combo, 33,  384, 256, tw0, 70,
                                         blist0, bincnt, 0, stats);
  k_cluster<<<NROW/16, 256, 0, stream>>>(combo, 289, 384, 64,  tw1, 900,
                                         blist1, bincnt, 1, stats);
  k_cluster<<<NROW/16, 256, 0, stream>>>(combo, 353, 384, 16,  tw2, 19000,
                                         blist2, bincnt, 2, stats);
  k_tlogit<<<NROW/4, 256, 0, stream>>>(tgtmap, combo, tw0, tw1, tw2, tlog);
  k_final<<<NROW/256, 256, 0, stream>>>(combo, stats, tlog, tgtmap, outF);
}

// Round 11
// 1516.482 us; speedup vs baseline: 1.1077x; 1.0080x over previous
//
#include <hip/hip_runtime.h>
#include <hip/hip_bf16.h>
#include <math.h>

#define BB 32
#define SS 256
#define EE 512
#define HH 1024
#define LDM 256
#define NROW (BB*SS)   // 8192

typedef __attribute__((ext_vector_type(8))) short bf16x8;
typedef __attribute__((ext_vector_type(4))) float f32x4;
typedef unsigned long long u64;

static __device__ inline unsigned short f2bf(float f){
  unsigned u = __float_as_uint(f);
  unsigned r = (u + 0x7fffu + ((u >> 16) & 1u)) >> 16;
  return (unsigned short)r;
}
// cheap round (no tie-to-even) for GEMM staging
static __device__ inline unsigned short f2bf_fast(float f){
  return (unsigned short)((__float_as_uint(f) + 0x8000u) >> 16);
}
static __device__ inline bf16x8 cvt8(float4 x, float4 y){
  union { ushort s[8]; bf16x8 v; } t;
  t.s[0]=f2bf_fast(x.x); t.s[1]=f2bf_fast(x.y); t.s[2]=f2bf_fast(x.z); t.s[3]=f2bf_fast(x.w);
  t.s[4]=f2bf_fast(y.x); t.s[5]=f2bf_fast(y.y); t.s[6]=f2bf_fast(y.z); t.s[7]=f2bf_fast(y.w);
  return t.v;
}
static __device__ inline unsigned packbf(float a, float b){
  return (unsigned)f2bf(a) | ((unsigned)f2bf(b) << 16);
}

// fast tanh: 1 - 2/(e^{2x}+1)
static __device__ inline float ftanh(float x){
  float e = __expf(2.f*x);
  return 1.f - 2.f/(e + 1.f);
}

// coherent (L1/L2-bypass, LLC-read) 16B load on the NORMAL coalescing path.
// Result lands asynchronously: caller must s_waitcnt vmcnt(0) + sched_barrier
// before first use.
#define GLD(dst, p) asm volatile("global_load_dwordx4 %0, %1, off sc0 sc1" \
                                 : "=v"(dst) : "v"(p) : "memory")

static __device__ inline bf16x8 asbf(f32x4 x){
  union { f32x4 f; bf16x8 b; } u; u.f = x; return u.b;
}

// ---------------- sort (stable argsort by descending length) ----------------
__global__ void k_sort(const int* __restrict__ length, int* __restrict__ sorted_idx){
  int b = threadIdx.x;
  if (b >= BB) return;
  int lb = length[b];
  int r = 0;
  for (int o = 0; o < BB; ++o){
    int lo = length[o];
    if (lo > lb || (lo == lb && o < b)) ++r;
  }
  sorted_idx[r] = b;
}

// token / target maps in sorted order
__global__ void k_maps(const int* __restrict__ sorted_idx,
                       const int* __restrict__ inp_seq, const int* __restrict__ tgt_seq,
                       int* __restrict__ tokmap, int* __restrict__ tgtmap){
  int bs = blockIdx.x; int t = threadIdx.x;
  int b = sorted_idx[bs];
  tokmap[bs*SS + t] = inp_seq[b*SS + t];
  tgtmap[bs*SS + t] = tgt_seq[b*SS + t];
}

// hid = z @ l2h_w.T + l2h_b, written DIRECTLY in bf16 fragment-major layout
__global__ __launch_bounds__(256) void k_hid(const float* __restrict__ z,
        const float* __restrict__ w, const float* __restrict__ bias,
        ushort* __restrict__ hb0){
  int id = blockIdx.x*256 + threadIdx.x;      // flat [B,2H] index = b*2048 + c
  int b = id >> 11, c = id & 2047;
  const float4* zr = (const float4*)(z + b*LDM);
  const float4* wr = (const float4*)(w + (size_t)c*LDM);
  float a0=0,a1=0,a2=0,a3=0;
  #pragma unroll 4
  for (int k=0;k<LDM/4;k++){ float4 zz=zr[k], ww=wr[k];
    a0+=zz.x*ww.x; a1+=zz.y*ww.y; a2+=zz.z*ww.z; a3+=zz.w*ww.w; }
  float val = a0+a1+a2+a3 + bias[c];
  int layer = id >> 15, bp = (id >> 10) & 31, j = id & 1023;
  hb0[(layer<<15) + ((j>>3)<<8) + (bp<<3) + (j&7)] = f2bf(val);
}

// concat [head_w(33); p0(256); p1(64); p2(16); zeros(15)] -> wcat[384][1024]
__global__ __launch_bounds__(256) void k_wcat(
    const float* __restrict__ head_w, const float* __restrict__ p0,
    const float* __restrict__ p1, const float* __restrict__ p2,
    float* __restrict__ wcat){
  int row = blockIdx.x; int t = threadIdx.x;
  float4* dst = (float4*)(wcat + (size_t)row*HH);
  const float* src;
  if      (row < 33)  src = head_w + (size_t)row*HH;
  else if (row < 289) src = p0 + (size_t)(row-33)*HH;
  else if (row < 353) src = p1 + (size_t)(row-289)*HH;
  else if (row < 369) src = p2 + (size_t)(row-353)*HH;
  else { dst[t] = make_float4(0.f,0.f,0.f,0.f); return; }
  dst[t] = ((const float4*)src)[t];
}

// bucket unmasked rows by target cluster (ballot-aggregated atomics)
__global__ __launch_bounds__(256) void k_bin(
    const int* __restrict__ tgtmap, int* __restrict__ cnt,
    int* __restrict__ l0, int* __restrict__ l1, int* __restrict__ l2)
{
  int row = blockIdx.x*256 + threadIdx.x;
  int tgt = tgtmap[row];
  int ci = (tgt == 0) ? -1 : (tgt >= 1000) ? 2 : (tgt >= 100) ? 1 : (tgt >= 30) ? 0 : -1;
  int lane = threadIdx.x & 63;
  #pragma unroll
  for (int c = 0; c < 3; ++c){
    unsigned long long mask = __ballot(ci == c);
    int nc = __popcll(mask);
    int base = 0;
    if (lane == 0 && nc) base = atomicAdd(&cnt[c], nc);
    base = __shfl(base, 0);
    if (ci == c){
      int pos = __popcll(mask & ((1ull << lane) - 1ull));
      int* lst = (c == 0) ? l0 : (c == 1) ? l1 : l2;
      lst[base + pos] = row;
    }
  }
}

// ---------------- bf16 MFMA GEMM: C[M,N] = A[M,K] @ Bm[N,K]^T (+bias0+bias1)
// abf16: A is already bf16 (ushort, row-major, lda elems) -> staging is a copy.
__global__ __launch_bounds__(256) void k_gemm_bf16(
    const float* __restrict__ A, int lda, const int* __restrict__ rowmap, int abf16,
    const float* __restrict__ Bm,
    const float* __restrict__ bias0, const float* __restrict__ bias1,
    float* __restrict__ C, int M, int N, int K)
{
  __shared__ ushort As[128*72];   // pad 64->72 elems: frag reads 2-way (free)
  __shared__ ushort Bs[128*72];
  const int nt = blockIdx.x * 128, mt = blockIdx.y * 128;
  const int tid = threadIdx.x;
  const int wv = tid >> 6, ln = tid & 63;
  const int wm = wv & 1, wn = wv >> 1;          // 2x2 wave grid (64x64 each)
  const int lc = ln & 15, quad = ln >> 4;
  f32x4 acc[4][4] = {{{0.f,0.f,0.f,0.f}}};

  for (int s = 0; s < K; s += 64){
    __syncthreads();
    #pragma unroll
    for (int cc = 0; cc < 4; ++cc){
      int ch = tid*4 + cc;                 // 0..1023: row=ch>>3, chunk=ch&7
      int r = ch >> 3, c = ch & 7;
      int ar = mt + r;
      if (abf16){
        const ushort* ap = (const ushort*)A + (size_t)ar*lda + s + c*8;
        *(bf16x8*)&As[r*72 + c*8] = *(const bf16x8*)ap;
      } else {
        const float* ap = A + (size_t)(rowmap ? rowmap[ar] : ar)*lda + s + c*8;
        float4 x = *(const float4*)ap, y = *(const float4*)(ap+4);
        *(bf16x8*)&As[r*72 + c*8] = cvt8(x, y);
      }
      int br = nt + r; if (br >= N) br = N - 1;
      const float* bp = Bm + (size_t)br*K + s + c*8;
      float4 bx = *(const float4*)bp, by = *(const float4*)(bp+4);
      *(bf16x8*)&Bs[r*72 + c*8] = cvt8(bx, by);
    }
    __syncthreads();
    #pragma unroll
    for (int kq = 0; kq < 2; ++kq){
      int cq = kq*4 + quad;
      bf16x8 af[4], bfv[4];
      #pragma unroll
      for (int i=0;i<4;i++) af[i]  = *(const bf16x8*)&As[(wm*64 + i*16 + lc)*72 + cq*8];
      #pragma unroll
      for (int j=0;j<4;j++) bfv[j] = *(const bf16x8*)&Bs[(wn*64 + j*16 + lc)*72 + cq*8];
      #pragma unroll
      for (int i=0;i<4;i++)
        #pragma unroll
        for (int j=0;j<4;j++)
          acc[i][j] = __builtin_amdgcn_mfma_f32_16x16x32_bf16(af[i], bfv[j], acc[i][j], 0, 0, 0);
    }
  }
  #pragma unroll
  for (int j=0;j<4;j++){
    int col = nt + wn*64 + j*16 + lc;
    if (col < N){
      float badd = (bias0 ? bias0[col] : 0.f) + (bias1 ? bias1[col] : 0.f);
      #pragma unroll
      for (int i=0;i<4;i++){
        int row = mt + wm*64 + i*16 + quad*4;
        #pragma unroll
        for (int r=0;r<4;r++)
          C[(size_t)(row+r)*N + col] = acc[i][j][r] + badd;
      }
    }
  }
}

// ---------------- split-role pipelined persistent RNN recurrence ----------------
// 128 WGs. WGs 0..63 (role L1) own 16 cols of h1; WGs 64..127 (role L2) own 16
// cols of h2, one step behind. Each role's inner loop is the PROVEN R6 loop
// (GLD sc0/sc1, single vmcnt(0)+sched_barrier, LDS weights, agent store, drain,
// sync, tid0 bump to 8x 128B-strided sub-counters, tid<16 poll, sync).
//   L1 round t: h1[t] = tanh(pre0[t] + h1[t-1] @ W0hh^T)         -> bump ctr1
//   L2 round s: h2[s] = tanh(b1 + h1[s] @ W1ih^T + h2[s-1] @ W1hh^T) -> bump ctr2
// Buffers: h1 TRIPLE-buffered (t%3), h2 ping-pong (s&1). Gates (lap-verified):
//   L1 end-of-round-t poll: ctr1>=8(t+1) [next a-loads], ctr2>=8(t-1) [buf reuse:
//     h1 buf (t+1)%3 held h1[t-2], consumed by L2 round t-2 -> ctr2=8(t-1)]
//   L2 pre-loop poll: ctr1>=8 [h1[0] durable]
//   L2 end-of-round-s poll: ctr1>=8(s+2) [h1[s+1]], ctr2>=8(s+1) [h2 buf reuse]
// Deadlock-free: L1 rounds 0..2 have trivial gates; L2 trails L1 by ~1 round;
// L1 can lead L2 by at most 3 (ctr2 gate), within the 3-deep h1 buffer.
// Removes layer-2's 32 MFMAs + reduce + drain from the h1 gating chain; the
// poll-detect RTT overlaps the other role's compute.
__global__ __launch_bounds__(256, 1) void k_rnn_split(
    const float* __restrict__ pre0, ushort* __restrict__ h2out,
    const float* __restrict__ w0hh, const float* __restrict__ w1ih,
    const float* __restrict__ w1hh,
    const float* __restrict__ b1ih, const float* __restrict__ b1hh,
    const ushort* __restrict__ hb0, ushort* __restrict__ hx, int* flags)
{
  __shared__ ushort w0F[16384], wiF[16384], whF[16384];  // frag-order weight slices
  __shared__ float red[2176];                            // [wv][row 0..31][17]
  const int wg  = blockIdx.x;
  const int tid = threadIdx.x;
  const bool roleL2 = wg >= 64;
  const int cw  = roleL2 ? wg - 64 : wg;
  const int j0  = cw * 16;
  int* myctr = flags + (roleL2 ? 256 : 0) + (cw & 7) * 32;

  // stage this role's 16x1024 weight slices as bf16 in MFMA fragment order
  for (int c = tid; c < 4096; c += 256){
    int rr = c >> 8, cc = (c & 255) * 4;
    int dst = ((cc >> 3)*16 + rr)*8 + (cc & 7);
    size_t srow = (size_t)(j0 + rr)*HH + cc;
    float4 w4; uint2 p;
    if (!roleL2){
      w4 = *(const float4*)&w0hh[srow];
      p.x = packbf(w4.x, w4.y); p.y = packbf(w4.z, w4.w);
      *(uint2*)&w0F[dst] = p;
    } else {
      w4 = *(const float4*)&w1ih[srow];
      p.x = packbf(w4.x, w4.y); p.y = packbf(w4.z, w4.w);
      *(uint2*)&wiF[dst] = p;
      w4 = *(const float4*)&w1hh[srow];
      p.x = packbf(w4.x, w4.y); p.y = packbf(w4.z, w4.w);
      *(uint2*)&whF[dst] = p;
    }
  }
  const int lane = tid & 63, wv = tid >> 6;
  const int col = lane & 15, quad = lane >> 4;
  const int ob = tid >> 3, oj = (tid << 1) & 15;
  const int ro = ob*17 + oj;
  const int k = j0 + oj;
  const unsigned off = ((unsigned)(k >> 3) << 7) + ((unsigned)ob << 2) + ((unsigned)(k & 7) >> 1);
  ushort* h1buf = hx;                 // 3 x 32768
  ushort* h2buf = hx + 3*32768;       // 2 x 32768

  if (!roleL2){
    // ---------------- role L1: the h1 chain ----------------
    float2 pre = *(const float2*)&pre0[((size_t)ob*SS + 0)*HH + j0 + oj];
    __syncthreads();
    for (int t = 0; t < SS; ++t){
      const u64* s1 = (const u64*)(t == 0 ? hb0 : h1buf + ((t+2)%3)*32768);
      f32x4 a0r[8], a1r[8];
      #pragma unroll
      for (int ks = 0; ks < 8; ++ks){
        int kb = wv*32 + ks*4 + quad;
        const u64* p = s1 + (kb << 6) + (col << 1);
        GLD(a0r[ks], p);
        GLD(a1r[ks], p + 32);
      }
      asm volatile("s_waitcnt vmcnt(0)" ::: "memory");
      __builtin_amdgcn_sched_barrier(0);

      f32x4 acc0 = {0.f,0.f,0.f,0.f}, acc1 = {0.f,0.f,0.f,0.f};
      #pragma unroll
      for (int ks = 0; ks < 8; ++ks){
        int kb = wv*32 + ks*4 + quad;
        bf16x8 b0 = *(const bf16x8*)&w0F[(kb*16 + col)*8];
        acc0 = __builtin_amdgcn_mfma_f32_16x16x32_bf16(asbf(a0r[ks]), b0, acc0, 0, 0, 0);
        acc1 = __builtin_amdgcn_mfma_f32_16x16x32_bf16(asbf(a1r[ks]), b0, acc1, 0, 0, 0);
      }
      #pragma unroll
      for (int q = 0; q < 4; ++q){
        red[wv*544 + (quad*4 + q)*17 + col]      = acc0[q];
        red[wv*544 + (16 + quad*4 + q)*17 + col] = acc1[q];
      }
      __syncthreads();
      float s0 = red[ro]   + red[544 + ro]   + red[1088 + ro]   + red[1632 + ro];
      float s1v= red[ro+1] + red[544 + ro+1] + red[1088 + ro+1] + red[1632 + ro+1];
      unsigned pk = packbf(ftanh(pre.x + s0), ftanh(pre.y + s1v));
      __hip_atomic_store((unsigned*)(h1buf + (t%3)*32768) + off, pk,
                         __ATOMIC_RELAXED, __HIP_MEMORY_SCOPE_AGENT);
      asm volatile("s_waitcnt vmcnt(0)" ::: "memory");
      __syncthreads();
      if (tid == 0)
        __hip_atomic_fetch_add(myctr, 1, __ATOMIC_RELAXED, __HIP_MEMORY_SCOPE_AGENT);

      int tn = (t + 1 < SS) ? t + 1 : SS - 1;
      pre = *(const float2*)&pre0[((size_t)ob*SS + tn)*HH + j0 + oj];

      if (t < SS - 1 && tid < 16){
        int tv = (tid < 8) ? 8*(t+1) : 8*(t-1);
        const int* fp = flags + ((tid < 8) ? 0 : 256) + (tid & 7)*32;
        if (tv > 0)
          while (__hip_atomic_load(fp, __ATOMIC_RELAXED, __HIP_MEMORY_SCOPE_AGENT) < tv) {}
      }
      __syncthreads();
    }
  } else {
    // ---------------- role L2: the h2 chain (one step behind) ----------------
    float2 pre2;
    pre2.x = b1ih[j0+oj]   + b1hh[j0+oj];
    pre2.y = b1ih[j0+oj+1] + b1hh[j0+oj+1];
    __syncthreads();
    // pre-loop gate: h1[0] fully stored
    if (tid < 8){
      while (__hip_atomic_load(flags + tid*32, __ATOMIC_RELAXED,
                               __HIP_MEMORY_SCOPE_AGENT) < 8) {}
    }
    __syncthreads();
    for (int s = 0; s < SS; ++s){
      const u64* sa = (const u64*)(h1buf + (s%3)*32768);                  // h1[s]
      const u64* sc = (const u64*)(s == 0 ? hb0 + 32768
                                          : h2buf + ((s+1)&1)*32768);     // h2[s-1]
      f32x4 a0r[8], a1r[8], c0r[8], c1r[8];
      #pragma unroll
      for (int ks = 0; ks < 8; ++ks){
        int kb = wv*32 + ks*4 + quad;
        const u64* p = sa + (kb << 6) + (col << 1);
        GLD(a0r[ks], p);
        GLD(a1r[ks], p + 32);
      }
      #pragma unroll
      for (int ks = 0; ks < 8; ++ks){
        int kb = wv*32 + ks*4 + quad;
        const u64* p = sc + (kb << 6) + (col << 1);
        GLD(c0r[ks], p);
        GLD(c1r[ks], p + 32);
      }
      asm volatile("s_waitcnt vmcnt(0)" ::: "memory");
      __builtin_amdgcn_sched_barrier(0);

      f32x4 acc0 = {0.f,0.f,0.f,0.f}, acc1 = {0.f,0.f,0.f,0.f};
      #pragma unroll
      for (int ks = 0; ks < 8; ++ks){
        int kb = wv*32 + ks*4 + quad;
        bf16x8 bi = *(const bf16x8*)&wiF[(kb*16 + col)*8];
        acc0 = __builtin_amdgcn_mfma_f32_16x16x32_bf16(asbf(a0r[ks]), bi, acc0, 0, 0, 0);
        acc1 = __builtin_amdgcn_mfma_f32_16x16x32_bf16(asbf(a1r[ks]), bi, acc1, 0, 0, 0);
        bf16x8 bh = *(const bf16x8*)&whF[(kb*16 + col)*8];
        acc0 = __builtin_amdgcn_mfma_f32_16x16x32_bf16(asbf(c0r[ks]), bh, acc0, 0, 0, 0);
        acc1 = __builtin_amdgcn_mfma_f32_16x16x32_bf16(asbf(c1r[ks]), bh, acc1, 0, 0, 0);
      }
      #pragma unroll
      for (int q = 0; q < 4; ++q){
        red[wv*544 + (quad*4 + q)*17 + col]      = acc0[q];
        red[wv*544 + (16 + quad*4 + q)*17 + col] = acc1[q];
      }
      __syncthreads();
      float s2v = red[ro]   + red[544 + ro]   + red[1088 + ro]   + red[1632 + ro];
      float s3v = red[ro+1] + red[544 + ro+1] + red[1088 + ro+1] + red[1632 + ro+1];
      unsigned pk2 = packbf(ftanh(pre2.x + s2v), ftanh(pre2.y + s3v));
      __hip_atomic_store((unsigned*)(h2buf + (s&1)*32768) + off, pk2,
                         __ATOMIC_RELAXED, __HIP_MEMORY_SCOPE_AGENT);
      asm volatile("s_waitcnt vmcnt(0)" ::: "memory");
      __syncthreads();
      if (tid == 0)
        __hip_atomic_fetch_add(myctr, 1, __ATOMIC_RELAXED, __HIP_MEMORY_SCOPE_AGENT);

      // off-protocol (cached): bf16 h2 for the downstream combo GEMM
      *((unsigned*)h2out + (((size_t)ob*SS + s)*HH + j0 + oj) / 2) = pk2;

      if (s < SS - 1 && tid < 16){
        int tv = (tid < 8) ? 8*(s+2) : 8*(s+1);
        const int* fp = flags + ((tid < 8) ? 0 : 256) + (tid & 7)*32;
        while (__hip_atomic_load(fp, __ATOMIC_RELAXED, __HIP_MEMORY_SCOPE_AGENT) < tv) {}
      }
      __syncthreads();
    }
  }
}

// ---------------- cluster logsumexp over the BINNED row list (4 rows/wave) ----
__global__ __launch_bounds__(256) void k_cluster(
    const float* __restrict__ combo, int off, int ld, int Kp,
    const float* __restrict__ W, int Nc,
    const int* __restrict__ rowlist, const int* __restrict__ cntp, int ci,
    float* __restrict__ stats)
{
  __shared__ float ps[4][4][256];
  int lane = threadIdx.x & 63;
  int wvl  = threadIdx.x >> 6;
  int n0 = (blockIdx.x*4 + wvl) * 4;
  int count = cntp[ci];
  int rows[4];
  #pragma unroll
  for (int r=0;r<4;r++){
    rows[r] = (n0 + r < count) ? rowlist[n0 + r] : -1;
    if (rows[r] >= 0)
      for (int k=lane;k<Kp;k+=64)
        ps[wvl][r][k] = combo[(size_t)rows[r]*ld + off + k];
  }
  __syncthreads();
  if (rows[0] < 0) return;          // list is compact: all 4 invalid together

  float mx[4], sm[4];
  #pragma unroll
  for (int r=0;r<4;r++){ mx[r]=-1e30f; sm[r]=0.f; }
  for (int n=lane; n<Nc; n+=64){
    const float* wr = W + (size_t)n*Kp;
    float l[4]={0.f,0.f,0.f,0.f};
    for (int k=0;k<Kp;k+=4){
      float4 w4 = *(const float4*)(wr+k);
      #pragma unroll
      for (int r=0;r<4;r++){
        l[r] += w4.x*ps[wvl][r][k] + w4.y*ps[wvl][r][k+1]
              + w4.z*ps[wvl][r][k+2] + w4.w*ps[wvl][r][k+3];
      }
    }
    #pragma unroll
    for (int r=0;r<4;r++){
      float nm = fmaxf(mx[r], l[r]);
      sm[r] = sm[r]*__expf(mx[r]-nm) + __expf(l[r]-nm);
      mx[r] = nm;
    }
  }
  #pragma unroll
  for (int r=0;r<4;r++){
    for (int off2=32; off2; off2>>=1){
      float om = __shfl_down(mx[r], off2);
      float os = __shfl_down(sm[r], off2);
      float nm = fmaxf(mx[r], om);
      sm[r] = sm[r]*__expf(mx[r]-nm) + os*__expf(om-nm);
      mx[r] = nm;
    }
    if (lane==0 && rows[r] >= 0){
      stats[(size_t)rows[r]*6 + ci*2 + 0] = mx[r];
      stats[(size_t)rows[r]*6 + ci*2 + 1] = sm[r];
    }
  }
}

// ---------------- target logit for tail clusters (one wave per row) ----------------
__global__ __launch_bounds__(256) void k_tlogit(
    const int* __restrict__ tgtmap, const float* __restrict__ combo,
    const float* __restrict__ w0, const float* __restrict__ w1, const float* __restrict__ w2,
    float* __restrict__ tlogit)
{
  int lane = threadIdx.x & 63;
  int row = (blockIdx.x * 256 + threadIdx.x) >> 6;
  int tgt = tgtmap[row];
  float acc = 0.f;
  const float* pr = nullptr; const float* wr = nullptr; int Kp = 0;
  const float* crow = combo + (size_t)row*384;
  if      (tgt >= 1000){ pr = crow + 353; wr = w2 + (size_t)(tgt-1000)*16;  Kp=16;  }
  else if (tgt >= 100) { pr = crow + 289; wr = w1 + (size_t)(tgt-100)*64;   Kp=64;  }
  else if (tgt >= 30)  { pr = crow + 33;  wr = w0 + (size_t)(tgt-30)*256;   Kp=256; }
  for (int k=lane; k<Kp; k+=64) acc += pr[k]*wr[k];
  for (int off=32; off; off>>=1) acc += __shfl_down(acc, off);
  if (lane==0) tlogit[row] = acc;
}

// ---------------- final: head LSE + assemble NLL, reduce ----------------
__global__ __launch_bounds__(256) void k_final(
    const float* __restrict__ combo, const float* __restrict__ stats,
    const float* __restrict__ tlogit, const int* __restrict__ tgtmap,
    float* __restrict__ out)
{
  int row = blockIdx.x*256 + threadIdx.x;
  int tgt = tgtmap[row];
  float nll = 0.f;
  if (tgt != 0){
    const float* hrow = combo + (size_t)row*384;
    float m = hrow[0];
    #pragma unroll
    for (int i=1;i<33;i++) m = fmaxf(m, hrow[i]);
    float s = 0.f;
    #pragma unroll
    for (int i=0;i<33;i++) s += __expf(hrow[i]-m);
    float lse = __logf(s) + m;
    int ci = (tgt>=1000) ? 2 : (tgt>=100) ? 1 : (tgt>=30) ? 0 : -1;
    if (ci < 0){
      nll = lse - hrow[tgt];
    } else {
      float cm = stats[(size_t)row*6 + ci*2 + 0];
      float cs = stats[(size_t)row*6 + ci*2 + 1];
      nll = lse - hrow[30+ci] + (__logf(cs) + cm - tlogit[row]);
    }
  }
  float v = nll;
  for (int off=32; off; off>>=1) v += __shfl_down(v, off);
  __shared__ float wsum[4];
  int lane = threadIdx.x & 63, wv = threadIdx.x >> 6;
  if (lane==0) wsum[wv] = v;
  __syncthreads();
  if (threadIdx.x==0) atomicAdd(out, wsum[0]+wsum[1]+wsum[2]+wsum[3]);
}

extern "C" void kernel_launch(void* const* d_in, const int* in_sizes, int n_in,
                              void* d_out, int out_size, void* d_ws, size_t ws_size,
                              hipStream_t stream)
{
  const float* z      = (const float*)d_in[0];
  const float* emb    = (const float*)d_in[1];
  const float* l2h_w  = (const float*)d_in[2];
  const float* l2h_b  = (const float*)d_in[3];
  const float* w0ih   = (const float*)d_in[4];
  const float* w0hh   = (const float*)d_in[5];
  const float* b0ih   = (const float*)d_in[6];
  const float* b0hh   = (const float*)d_in[7];
  const float* w1ih   = (const float*)d_in[8];
  const float* w1hh   = (const float*)d_in[9];
  const float* b1ih   = (const float*)d_in[10];
  const float* b1hh   = (const float*)d_in[11];
  const float* head_w = (const float*)d_in[12];
  const float* p0     = (const float*)d_in[13];
  const float* tw0    = (const float*)d_in[14];
  const float* p1     = (const float*)d_in[15];
  const float* tw1    = (const float*)d_in[16];
  const float* p2     = (const float*)d_in[17];
  const float* tw2    = (const float*)d_in[18];
  const int* inp_seq  = (const int*)d_in[19];
  const int* tgt_seq  = (const int*)d_in[20];
  const int* length   = (const int*)d_in[21];

  float* ws   = (float*)d_ws;
  ushort* hb0 = (ushort*)ws;                      // 65536 ushorts (2 layers initial)
  ushort* hx  = hb0 + 65536;                      // 163840 ushorts: h1 x3, h2 x2
  float* bufA = ws + 114688;                      // 8192*1024 fp32 (pre0; later combo etc.)
  ushort* hbB = (ushort*)(bufA + (size_t)NROW*HH); // 8192*1024 bf16 (h2)
  int*   ibuf = (int*)(hbB + (size_t)NROW*HH);
  int* sorted_idx = ibuf;                         // 32
  int* tokmap = ibuf + 32;                        // 8192
  int* tgtmap = tokmap + NROW;                    // 8192
  int* flags  = tgtmap + NROW;                    // 512 ints: ctr1[8] + ctr2[8] @128B
  int* bincnt = flags + 512;                      // 3 (+pad to 32)
  int* blist0 = bincnt + 32;                      // 8192
  int* blist1 = blist0 + NROW;                    // 8192
  int* blist2 = blist1 + NROW;                    // 8192
  float* combo = bufA;                            // 8192*384 (head 0..32 | p0 33..288 | p1 289..352 | p2 353..368)
  float* stats = bufA + (size_t)NROW*384;         // 8192*6
  float* tlog  = stats + (size_t)NROW*6;          // 8192
  float* wcat  = tlog + NROW;                     // 384*1024

  float* outF = (float*)d_out;
  hipMemsetAsync(outF, 0, sizeof(float), stream);
  hipMemsetAsync(flags, 0, 544*sizeof(int), stream);

  k_sort<<<1, 32, 0, stream>>>(length, sorted_idx);
  k_maps<<<32, 256, 0, stream>>>(sorted_idx, inp_seq, tgt_seq, tokmap, tgtmap);
  k_hid<<<256, 256, 0, stream>>>(z, l2h_w, l2h_b, hb0);
  k_bin<<<32, 256, 0, stream>>>(tgtmap, bincnt, blist0, blist1, blist2);

  // pre0 = emb[tok] @ w0ih^T + b0ih + b0hh   (bf16 MFMA, A gathered fp32)
  k_gemm_bf16<<<dim3(HH/128, NROW/128), 256, 0, stream>>>(emb, EE, tokmap, 0, w0ih,
                                                          b0ih, b0hh, bufA, NROW, HH, EE);
  // split-role pipelined recurrence: hbB := h2 (bf16)
  k_rnn_split<<<128, 256, 0, stream>>>(bufA, hbB, w0hh, w1ih, w1hh, b1ih, b1hh,
                                       hb0, hx, flags);

  // single fused output GEMM: combo = h2 @ [head;p0;p1;p2]^T (A already bf16)
  k_wcat<<<384, 256, 0, stream>>>(head_w, p0, p1, p2, wcat);
  k_gemm_bf16<<<dim3(3, NROW/128), 256, 0, stream>>>((const float*)hbB, HH, nullptr, 1,
                                                     wcat, nullptr, nullptr,
                                                     combo, NROW, 384, HH);

  // cluster LSE only for rows whose TARGET is in that cluster (binned lists)
  k_cluster<<<NROW/16, 256, 0, stream>>>(combo, 33,  384, 256, tw0, 70,
                                         blist0, bincnt, 0, stats);
  k_cluster<<<NROW/16, 256, 0, stream>>>(combo, 289, 384, 64,  tw1, 900,
                                         blist1, bincnt, 1, stats);
  k_cluster<<<NROW/16, 256, 0, stream>>>(combo, 353, 384, 16,  tw2, 19000,
                                         blist2, bincnt, 2, stats);
  k_tlogit<<<NROW/4, 256, 0, stream>>>(tgtmap, combo, tw0, tw1, tw2, tlog);
  k_final<<<NROW/256, 256, 0, stream>>>(combo, stats, tlog, tgtmap, outF);
}

// Round 12
// 1479.664 us; speedup vs baseline: 1.1353x; 1.0249x over previous
//
#include <hip/hip_runtime.h>
#include <hip/hip_bf16.h>
#include <math.h>

#define BB 32
#define SS 256
#define EE 512
#define HH 1024
#define LDM 256
#define NROW (BB*SS)   // 8192

typedef __attribute__((ext_vector_type(8))) short bf16x8;
typedef __attribute__((ext_vector_type(4))) float f32x4;
typedef unsigned long long u64;

static __device__ inline unsigned short f2bf(float f){
  unsigned u = __float_as_uint(f);
  unsigned r = (u + 0x7fffu + ((u >> 16) & 1u)) >> 16;
  return (unsigned short)r;
}
// cheap round (no tie-to-even) for GEMM staging
static __device__ inline unsigned short f2bf_fast(float f){
  return (unsigned short)((__float_as_uint(f) + 0x8000u) >> 16);
}
static __device__ inline bf16x8 cvt8(float4 x, float4 y){
  union { ushort s[8]; bf16x8 v; } t;
  t.s[0]=f2bf_fast(x.x); t.s[1]=f2bf_fast(x.y); t.s[2]=f2bf_fast(x.z); t.s[3]=f2bf_fast(x.w);
  t.s[4]=f2bf_fast(y.x); t.s[5]=f2bf_fast(y.y); t.s[6]=f2bf_fast(y.z); t.s[7]=f2bf_fast(y.w);
  return t.v;
}
static __device__ inline unsigned packbf(float a, float b){
  return (unsigned)f2bf(a) | ((unsigned)f2bf(b) << 16);
}

// fast tanh: 1 - 2/(e^{2x}+1)
static __device__ inline float ftanh(float x){
  float e = __expf(2.f*x);
  return 1.f - 2.f/(e + 1.f);
}

// coherent (L1/L2-bypass, LLC-read) 16B load on the NORMAL coalescing path.
// Result lands asynchronously: caller must s_waitcnt vmcnt(0) + sched_barrier
// before first use.
#define GLD(dst, p) asm volatile("global_load_dwordx4 %0, %1, off sc0 sc1" \
                                 : "=v"(dst) : "v"(p) : "memory")

static __device__ inline bf16x8 asbf(f32x4 x){
  union { f32x4 f; bf16x8 b; } u; u.f = x; return u.b;
}

// ---------------- fused prep: sort + token/target maps + maxlen + cluster bins ----
__global__ __launch_bounds__(256) void k_prep(
    const int* __restrict__ length,
    const int* __restrict__ inp_seq, const int* __restrict__ tgt_seq,
    int* __restrict__ tokmap, int* __restrict__ tgtmap,
    int* __restrict__ cnt, int* __restrict__ ml,
    int* __restrict__ l0, int* __restrict__ l1, int* __restrict__ l2)
{
  __shared__ int src_b;
  int bs = blockIdx.x, t = threadIdx.x;
  if (t < 32){
    int lb = length[t];
    int r = 0;
    for (int o = 0; o < BB; ++o){
      int lo = length[o];
      if (lo > lb || (lo == lb && o < t)) ++r;
    }
    if (r == bs) src_b = t;                  // exactly one writer (ranks are a permutation)
    if (bs == 0 && t == 0){
      int m = 0;
      for (int o = 0; o < BB; ++o){ int lo = length[o]; if (lo > m) m = lo; }
      *ml = m;
    }
  }
  __syncthreads();
  int b = src_b;
  int row = bs*SS + t;
  tokmap[row] = inp_seq[b*SS + t];
  int tgt = tgt_seq[b*SS + t];
  tgtmap[row] = tgt;
  int ci = (tgt == 0) ? -1 : (tgt >= 1000) ? 2 : (tgt >= 100) ? 1 : (tgt >= 30) ? 0 : -1;
  int lane = t & 63;
  #pragma unroll
  for (int c = 0; c < 3; ++c){
    unsigned long long mask = __ballot(ci == c);
    int nc = __popcll(mask);
    int base = 0;
    if (lane == 0 && nc) base = atomicAdd(&cnt[c], nc);
    base = __shfl(base, 0);
    if (ci == c){
      int pos = __popcll(mask & ((1ull << lane) - 1ull));
      int* lst = (c == 0) ? l0 : (c == 1) ? l1 : l2;
      lst[base + pos] = row;
    }
  }
}

// gather emb rows (sorted token order) -> bf16 tokemb[8192][512]
__global__ __launch_bounds__(256) void k_emb(
    const int* __restrict__ tokmap, const float* __restrict__ emb,
    ushort* __restrict__ tokemb)
{
  int row = blockIdx.x; int t = threadIdx.x;
  const float2* src = (const float2*)(emb + (size_t)tokmap[row]*EE);
  float2 v = src[t];
  ((unsigned*)tokemb)[(size_t)row*(EE/2) + t] = packbf(v.x, v.y);
}

// hid = z @ l2h_w.T + l2h_b, written DIRECTLY in bf16 fragment-major layout
__global__ __launch_bounds__(256) void k_hid(const float* __restrict__ z,
        const float* __restrict__ w, const float* __restrict__ bias,
        ushort* __restrict__ hb0){
  int id = blockIdx.x*256 + threadIdx.x;      // flat [B,2H] index = b*2048 + c
  int b = id >> 11, c = id & 2047;
  const float4* zr = (const float4*)(z + b*LDM);
  const float4* wr = (const float4*)(w + (size_t)c*LDM);
  float a0=0,a1=0,a2=0,a3=0;
  #pragma unroll 4
  for (int k=0;k<LDM/4;k++){ float4 zz=zr[k], ww=wr[k];
    a0+=zz.x*ww.x; a1+=zz.y*ww.y; a2+=zz.z*ww.z; a3+=zz.w*ww.w; }
  float val = a0+a1+a2+a3 + bias[c];
  int layer = id >> 15, bp = (id >> 10) & 31, j = id & 1023;
  hb0[(layer<<15) + ((j>>3)<<8) + (bp<<3) + (j&7)] = f2bf(val);
}

// concat [head_w(33); p0(256); p1(64); p2(16); zeros(15)] -> wcat[384][1024]
__global__ __launch_bounds__(256) void k_wcat(
    const float* __restrict__ head_w, const float* __restrict__ p0,
    const float* __restrict__ p1, const float* __restrict__ p2,
    float* __restrict__ wcat){
  int row = blockIdx.x; int t = threadIdx.x;
  float4* dst = (float4*)(wcat + (size_t)row*HH);
  const float* src;
  if      (row < 33)  src = head_w + (size_t)row*HH;
  else if (row < 289) src = p0 + (size_t)(row-33)*HH;
  else if (row < 353) src = p1 + (size_t)(row-289)*HH;
  else if (row < 369) src = p2 + (size_t)(row-353)*HH;
  else { dst[t] = make_float4(0.f,0.f,0.f,0.f); return; }
  dst[t] = ((const float4*)src)[t];
}

// ---------------- bf16 MFMA GEMM: C[M,N] = A[M,K] @ Bm[N,K]^T (+bias0+bias1)
// abf16: A is already bf16 (ushort, row-major, lda elems) -> staging is a copy.
__global__ __launch_bounds__(256) void k_gemm_bf16(
    const float* __restrict__ A, int lda, const int* __restrict__ rowmap, int abf16,
    const float* __restrict__ Bm,
    const float* __restrict__ bias0, const float* __restrict__ bias1,
    float* __restrict__ C, int M, int N, int K)
{
  __shared__ ushort As[128*72];   // pad 64->72 elems: frag reads 2-way (free)
  __shared__ ushort Bs[128*72];
  const int nt = blockIdx.x * 128, mt = blockIdx.y * 128;
  const int tid = threadIdx.x;
  const int wv = tid >> 6, ln = tid & 63;
  const int wm = wv & 1, wn = wv >> 1;          // 2x2 wave grid (64x64 each)
  const int lc = ln & 15, quad = ln >> 4;
  f32x4 acc[4][4] = {{{0.f,0.f,0.f,0.f}}};

  for (int s = 0; s < K; s += 64){
    __syncthreads();
    #pragma unroll
    for (int cc = 0; cc < 4; ++cc){
      int ch = tid*4 + cc;                 // 0..1023: row=ch>>3, chunk=ch&7
      int r = ch >> 3, c = ch & 7;
      int ar = mt + r;
      if (abf16){
        const ushort* ap = (const ushort*)A + (size_t)ar*lda + s + c*8;
        *(bf16x8*)&As[r*72 + c*8] = *(const bf16x8*)ap;
      } else {
        const float* ap = A + (size_t)(rowmap ? rowmap[ar] : ar)*lda + s + c*8;
        float4 x = *(const float4*)ap, y = *(const float4*)(ap+4);
        *(bf16x8*)&As[r*72 + c*8] = cvt8(x, y);
      }
      int br = nt + r; if (br >= N) br = N - 1;
      const float* bp = Bm + (size_t)br*K + s + c*8;
      float4 bx = *(const float4*)bp, by = *(const float4*)(bp+4);
      *(bf16x8*)&Bs[r*72 + c*8] = cvt8(bx, by);
    }
    __syncthreads();
    #pragma unroll
    for (int kq = 0; kq < 2; ++kq){
      int cq = kq*4 + quad;
      bf16x8 af[4], bfv[4];
      #pragma unroll
      for (int i=0;i<4;i++) af[i]  = *(const bf16x8*)&As[(wm*64 + i*16 + lc)*72 + cq*8];
      #pragma unroll
      for (int j=0;j<4;j++) bfv[j] = *(const bf16x8*)&Bs[(wn*64 + j*16 + lc)*72 + cq*8];
      #pragma unroll
      for (int i=0;i<4;i++)
        #pragma unroll
        for (int j=0;j<4;j++)
          acc[i][j] = __builtin_amdgcn_mfma_f32_16x16x32_bf16(af[i], bfv[j], acc[i][j], 0, 0, 0);
    }
  }
  #pragma unroll
  for (int j=0;j<4;j++){
    int col = nt + wn*64 + j*16 + lc;
    if (col < N){
      float badd = (bias0 ? bias0[col] : 0.f) + (bias1 ? bias1[col] : 0.f);
      #pragma unroll
      for (int i=0;i<4;i++){
        int row = mt + wm*64 + i*16 + quad*4;
        #pragma unroll
        for (int r=0;r<4;r++)
          C[(size_t)(row+r)*N + col] = acc[i][j][r] + badd;
      }
    }
  }
}

// ---------------- split-role pipelined persistent RNN recurrence ----------------
// EXACT R11 structure (proven, 1001us) with ONE delta: rounds bounded by
// ml = max(length) read from device (uniform across all WGs). Positions
// s >= ml are masked (tgt==0) in every downstream consumer (k_final guard;
// clusters/tlogit use tgt!=0 binned rows), so their h2 rows are never read.
__global__ __launch_bounds__(256, 1) void k_rnn_split(
    const float* __restrict__ pre0, ushort* __restrict__ h2out,
    const float* __restrict__ w0hh, const float* __restrict__ w1ih,
    const float* __restrict__ w1hh,
    const float* __restrict__ b1ih, const float* __restrict__ b1hh,
    const ushort* __restrict__ hb0, ushort* __restrict__ hx, int* flags,
    const int* __restrict__ mlp)
{
  __shared__ ushort w0F[16384], wiF[16384], whF[16384];  // frag-order weight slices
  __shared__ float red[2176];                            // [wv][row 0..31][17]
  const int wg  = blockIdx.x;
  const int tid = threadIdx.x;
  const bool roleL2 = wg >= 64;
  const int cw  = roleL2 ? wg - 64 : wg;
  const int j0  = cw * 16;
  const int ml  = *mlp;
  int* myctr = flags + (roleL2 ? 256 : 0) + (cw & 7) * 32;

  // stage this role's 16x1024 weight slices as bf16 in MFMA fragment order
  for (int c = tid; c < 4096; c += 256){
    int rr = c >> 8, cc = (c & 255) * 4;
    int dst = ((cc >> 3)*16 + rr)*8 + (cc & 7);
    size_t srow = (size_t)(j0 + rr)*HH + cc;
    float4 w4; uint2 p;
    if (!roleL2){
      w4 = *(const float4*)&w0hh[srow];
      p.x = packbf(w4.x, w4.y); p.y = packbf(w4.z, w4.w);
      *(uint2*)&w0F[dst] = p;
    } else {
      w4 = *(const float4*)&w1ih[srow];
      p.x = packbf(w4.x, w4.y); p.y = packbf(w4.z, w4.w);
      *(uint2*)&wiF[dst] = p;
      w4 = *(const float4*)&w1hh[srow];
      p.x = packbf(w4.x, w4.y); p.y = packbf(w4.z, w4.w);
      *(uint2*)&whF[dst] = p;
    }
  }
  const int lane = tid & 63, wv = tid >> 6;
  const int col = lane & 15, quad = lane >> 4;
  const int ob = tid >> 3, oj = (tid << 1) & 15;
  const int ro = ob*17 + oj;
  const int k = j0 + oj;
  const unsigned off = ((unsigned)(k >> 3) << 7) + ((unsigned)ob << 2) + ((unsigned)(k & 7) >> 1);
  ushort* h1buf = hx;                 // 3 x 32768
  ushort* h2buf = hx + 3*32768;       // 2 x 32768

  if (!roleL2){
    // ---------------- role L1: the h1 chain ----------------
    float2 pre = *(const float2*)&pre0[((size_t)ob*SS + 0)*HH + j0 + oj];
    __syncthreads();
    for (int t = 0; t < ml; ++t){
      const u64* s1 = (const u64*)(t == 0 ? hb0 : h1buf + ((t+2)%3)*32768);
      f32x4 a0r[8], a1r[8];
      #pragma unroll
      for (int ks = 0; ks < 8; ++ks){
        int kb = wv*32 + ks*4 + quad;
        const u64* p = s1 + (kb << 6) + (col << 1);
        GLD(a0r[ks], p);
        GLD(a1r[ks], p + 32);
      }
      asm volatile("s_waitcnt vmcnt(0)" ::: "memory");
      __builtin_amdgcn_sched_barrier(0);

      f32x4 acc0 = {0.f,0.f,0.f,0.f}, acc1 = {0.f,0.f,0.f,0.f};
      #pragma unroll
      for (int ks = 0; ks < 8; ++ks){
        int kb = wv*32 + ks*4 + quad;
        bf16x8 b0 = *(const bf16x8*)&w0F[(kb*16 + col)*8];
        acc0 = __builtin_amdgcn_mfma_f32_16x16x32_bf16(asbf(a0r[ks]), b0, acc0, 0, 0, 0);
        acc1 = __builtin_amdgcn_mfma_f32_16x16x32_bf16(asbf(a1r[ks]), b0, acc1, 0, 0, 0);
      }
      #pragma unroll
      for (int q = 0; q < 4; ++q){
        red[wv*544 + (quad*4 + q)*17 + col]      = acc0[q];
        red[wv*544 + (16 + quad*4 + q)*17 + col] = acc1[q];
      }
      __syncthreads();
      float s0 = red[ro]   + red[544 + ro]   + red[1088 + ro]   + red[1632 + ro];
      float s1v= red[ro+1] + red[544 + ro+1] + red[1088 + ro+1] + red[1632 + ro+1];
      unsigned pk = packbf(ftanh(pre.x + s0), ftanh(pre.y + s1v));
      __hip_atomic_store((unsigned*)(h1buf + (t%3)*32768) + off, pk,
                         __ATOMIC_RELAXED, __HIP_MEMORY_SCOPE_AGENT);
      asm volatile("s_waitcnt vmcnt(0)" ::: "memory");
      __syncthreads();
      if (tid == 0)
        __hip_atomic_fetch_add(myctr, 1, __ATOMIC_RELAXED, __HIP_MEMORY_SCOPE_AGENT);

      int tn = (t + 1 < ml) ? t + 1 : ml - 1;
      pre = *(const float2*)&pre0[((size_t)ob*SS + tn)*HH + j0 + oj];

      if (t < ml - 1 && tid < 16){
        int tv = (tid < 8) ? 8*(t+1) : 8*(t-1);
        const int* fp = flags + ((tid < 8) ? 0 : 256) + (tid & 7)*32;
        if (tv > 0)
          while (__hip_atomic_load(fp, __ATOMIC_RELAXED, __HIP_MEMORY_SCOPE_AGENT) < tv) {}
      }
      __syncthreads();
    }
  } else {
    // ---------------- role L2: the h2 chain (one step behind) ----------------
    float2 pre2;
    pre2.x = b1ih[j0+oj]   + b1hh[j0+oj];
    pre2.y = b1ih[j0+oj+1] + b1hh[j0+oj+1];
    __syncthreads();
    // pre-loop gate: h1[0] fully stored
    if (tid < 8){
      while (__hip_atomic_load(flags + tid*32, __ATOMIC_RELAXED,
                               __HIP_MEMORY_SCOPE_AGENT) < 8) {}
    }
    __syncthreads();
    for (int s = 0; s < ml; ++s){
      const u64* sa = (const u64*)(h1buf + (s%3)*32768);                  // h1[s]
      const u64* sc = (const u64*)(s == 0 ? hb0 + 32768
                                          : h2buf + ((s+1)&1)*32768);     // h2[s-1]
      f32x4 a0r[8], a1r[8], c0r[8], c1r[8];
      #pragma unroll
      for (int ks = 0; ks < 8; ++ks){
        int kb = wv*32 + ks*4 + quad;
        const u64* p = sa + (kb << 6) + (col << 1);
        GLD(a0r[ks], p);
        GLD(a1r[ks], p + 32);
      }
      #pragma unroll
      for (int ks = 0; ks < 8; ++ks){
        int kb = wv*32 + ks*4 + quad;
        const u64* p = sc + (kb << 6) + (col << 1);
        GLD(c0r[ks], p);
        GLD(c1r[ks], p + 32);
      }
      asm volatile("s_waitcnt vmcnt(0)" ::: "memory");
      __builtin_amdgcn_sched_barrier(0);

      f32x4 acc0 = {0.f,0.f,0.f,0.f}, acc1 = {0.f,0.f,0.f,0.f};
      #pragma unroll
      for (int ks = 0; ks < 8; ++ks){
        int kb = wv*32 + ks*4 + quad;
        bf16x8 bi = *(const bf16x8*)&wiF[(kb*16 + col)*8];
        acc0 = __builtin_amdgcn_mfma_f32_16x16x32_bf16(asbf(a0r[ks]), bi, acc0, 0, 0, 0);
        acc1 = __builtin_amdgcn_mfma_f32_16x16x32_bf16(asbf(a1r[ks]), bi, acc1, 0, 0, 0);
        bf16x8 bh = *(const bf16x8*)&whF[(kb*16 + col)*8];
        acc0 = __builtin_amdgcn_mfma_f32_16x16x32_bf16(asbf(c0r[ks]), bh, acc0, 0, 0, 0);
        acc1 = __builtin_amdgcn_mfma_f32_16x16x32_bf16(asbf(c1r[ks]), bh, acc1, 0, 0, 0);
      }
      #pragma unroll
      for (int q = 0; q < 4; ++q){
        red[wv*544 + (quad*4 + q)*17 + col]      = acc0[q];
        red[wv*544 + (16 + quad*4 + q)*17 + col] = acc1[q];
      }
      __syncthreads();
      float s2v = red[ro]   + red[544 + ro]   + red[1088 + ro]   + red[1632 + ro];
      float s3v = red[ro+1] + red[544 + ro+1] + red[1088 + ro+1] + red[1632 + ro+1];
      unsigned pk2 = packbf(ftanh(pre2.x + s2v), ftanh(pre2.y + s3v));
      __hip_atomic_store((unsigned*)(h2buf + (s&1)*32768) + off, pk2,
                         __ATOMIC_RELAXED, __HIP_MEMORY_SCOPE_AGENT);
      asm volatile("s_waitcnt vmcnt(0)" ::: "memory");
      __syncthreads();
      if (tid == 0)
        __hip_atomic_fetch_add(myctr, 1, __ATOMIC_RELAXED, __HIP_MEMORY_SCOPE_AGENT);

      // off-protocol (cached): bf16 h2 for the downstream combo GEMM
      *((unsigned*)h2out + (((size_t)ob*SS + s)*HH + j0 + oj) / 2) = pk2;

      if (s < ml - 1 && tid < 16){
        int tv = (tid < 8) ? 8*(s+2) : 8*(s+1);
        const int* fp = flags + ((tid < 8) ? 0 : 256) + (tid & 7)*32;
        while (__hip_atomic_load(fp, __ATOMIC_RELAXED, __HIP_MEMORY_SCOPE_AGENT) < tv) {}
      }
      __syncthreads();
    }
  }
}

// ---------------- cluster logsumexp over the BINNED row list (4 rows/wave) ----
__global__ __launch_bounds__(256) void k_cluster(
    const float* __restrict__ combo, int off, int ld, int Kp,
    const float* __restrict__ W, int Nc,
    const int* __restrict__ rowlist, const int* __restrict__ cntp, int ci,
    float* __restrict__ stats)
{
  __shared__ float ps[4][4][256];
  int lane = threadIdx.x & 63;
  int wvl  = threadIdx.x >> 6;
  int n0 = (blockIdx.x*4 + wvl) * 4;
  int count = cntp[ci];
  int rows[4];
  #pragma unroll
  for (int r=0;r<4;r++){
    rows[r] = (n0 + r < count) ? rowlist[n0 + r] : -1;
    if (rows[r] >= 0)
      for (int k=lane;k<Kp;k+=64)
        ps[wvl][r][k] = combo[(size_t)rows[r]*ld + off + k];
  }
  __syncthreads();
  if (rows[0] < 0) return;          // list is compact: all 4 invalid together

  float mx[4], sm[4];
  #pragma unroll
  for (int r=0;r<4;r++){ mx[r]=-1e30f; sm[r]=0.f; }
  for (int n=lane; n<Nc; n+=64){
    const float* wr = W + (size_t)n*Kp;
    float l[4]={0.f,0.f,0.f,0.f};
    for (int k=0;k<Kp;k+=4){
      float4 w4 = *(const float4*)(wr+k);
      #pragma unroll
      for (int r=0;r<4;r++){
        l[r] += w4.x*ps[wvl][r][k] + w4.y*ps[wvl][r][k+1]
              + w4.z*ps[wvl][r][k+2] + w4.w*ps[wvl][r][k+3];
      }
    }
    #pragma unroll
    for (int r=0;r<4;r++){
      float nm = fmaxf(mx[r], l[r]);
      sm[r] = sm[r]*__expf(mx[r]-nm) + __expf(l[r]-nm);
      mx[r] = nm;
    }
  }
  #pragma unroll
  for (int r=0;r<4;r++){
    for (int off2=32; off2; off2>>=1){
      float om = __shfl_down(mx[r], off2);
      float os = __shfl_down(sm[r], off2);
      float nm = fmaxf(mx[r], om);
      sm[r] = sm[r]*__expf(mx[r]-nm) + os*__expf(om-nm);
      mx[r] = nm;
    }
    if (lane==0 && rows[r] >= 0){
      stats[(size_t)rows[r]*6 + ci*2 + 0] = mx[r];
      stats[(size_t)rows[r]*6 + ci*2 + 1] = sm[r];
    }
  }
}

// ---------------- target logit for tail clusters (one wave per row) ----------------
__global__ __launch_bounds__(256) void k_tlogit(
    const int* __restrict__ tgtmap, const float* __restrict__ combo,
    const float* __restrict__ w0, const float* __restrict__ w1, const float* __restrict__ w2,
    float* __restrict__ tlogit)
{
  int lane = threadIdx.x & 63;
  int row = (blockIdx.x * 256 + threadIdx.x) >> 6;
  int tgt = tgtmap[row];
  float acc = 0.f;
  const float* pr = nullptr; const float* wr = nullptr; int Kp = 0;
  const float* crow = combo + (size_t)row*384;
  if      (tgt >= 1000){ pr = crow + 353; wr = w2 + (size_t)(tgt-1000)*16;  Kp=16;  }
  else if (tgt >= 100) { pr = crow + 289; wr = w1 + (size_t)(tgt-100)*64;   Kp=64;  }
  else if (tgt >= 30)  { pr = crow + 33;  wr = w0 + (size_t)(tgt-30)*256;   Kp=256; }
  for (int k=lane; k<Kp; k+=64) acc += pr[k]*wr[k];
  for (int off=32; off; off>>=1) acc += __shfl_down(acc, off);
  if (lane==0) tlogit[row] = acc;
}

// ---------------- final: head LSE + assemble NLL, reduce ----------------
__global__ __launch_bounds__(256) void k_final(
    const float* __restrict__ combo, const float* __restrict__ stats,
    const float* __restrict__ tlogit, const int* __restrict__ tgtmap,
    float* __restrict__ out)
{
  int row = blockIdx.x*256 + threadIdx.x;
  int tgt = tgtmap[row];
  float nll = 0.f;
  if (tgt != 0){
    const float* hrow = combo + (size_t)row*384;
    float m = hrow[0];
    #pragma unroll
    for (int i=1;i<33;i++) m = fmaxf(m, hrow[i]);
    float s = 0.f;
    #pragma unroll
    for (int i=0;i<33;i++) s += __expf(hrow[i]-m);
    float lse = __logf(s) + m;
    int ci = (tgt>=1000) ? 2 : (tgt>=100) ? 1 : (tgt>=30) ? 0 : -1;
    if (ci < 0){
      nll = lse - hrow[tgt];
    } else {
      float cm = stats[(size_t)row*6 + ci*2 + 0];
      float cs = stats[(size_t)row*6 + ci*2 + 1];
      nll = lse - hrow[30+ci] + (__logf(cs) + cm - tlogit[row]);
    }
  }
  float v = nll;
  for (int off=32; off; off>>=1) v += __shfl_down(v, off);
  __shared__ float wsum[4];
  int lane = threadIdx.x & 63, wv = threadIdx.x >> 6;
  if (lane==0) wsum[wv] = v;
  __syncthreads();
  if (threadIdx.x==0) atomicAdd(out, wsum[0]+wsum[1]+wsum[2]+wsum[3]);
}

extern "C" void kernel_launch(void* const* d_in, const int* in_sizes, int n_in,
                              void* d_out, int out_size, void* d_ws, size_t ws_size,
                              hipStream_t stream)
{
  const float* z      = (const float*)d_in[0];
  const float* emb    = (const float*)d_in[1];
  const float* l2h_w  = (const float*)d_in[2];
  const float* l2h_b  = (const float*)d_in[3];
  const float* w0ih   = (const float*)d_in[4];
  const float* w0hh   = (const float*)d_in[5];
  const float* b0ih   = (const float*)d_in[6];
  const float* b0hh   = (const float*)d_in[7];
  const float* w1ih   = (const float*)d_in[8];
  const float* w1hh   = (const float*)d_in[9];
  const float* b1ih   = (const float*)d_in[10];
  const float* b1hh   = (const float*)d_in[11];
  const float* head_w = (const float*)d_in[12];
  const float* p0     = (const float*)d_in[13];
  const float* tw0    = (const float*)d_in[14];
  const float* p1     = (const float*)d_in[15];
  const float* tw1    = (const float*)d_in[16];
  const float* p2     = (const float*)d_in[17];
  const float* tw2    = (const float*)d_in[18];
  const int* inp_seq  = (const int*)d_in[19];
  const int* tgt_seq  = (const int*)d_in[20];
  const int* length   = (const int*)d_in[21];

  float* ws   = (float*)d_ws;
  ushort* hb0 = (ushort*)ws;                      // 65536 ushorts (2 layers initial)
  ushort* hx  = hb0 + 65536;                      // 163840 ushorts: h1 x3, h2 x2
  float* bufA = ws + 114688;                      // 8192*1024 fp32 (pre0; later combo etc.)
  ushort* hbB = (ushort*)(bufA + (size_t)NROW*HH); // 8192*1024 bf16 (h2)
  ushort* tokemb = hbB + (size_t)NROW*HH;         // 8192*512 bf16 (gathered emb)
  int*   ibuf = (int*)(tokemb + (size_t)NROW*EE);
  int* sorted_idx = ibuf;                         // 32 (unused; kept for layout)
  int* tokmap = ibuf + 32;                        // 8192
  int* tgtmap = tokmap + NROW;                    // 8192
  int* flags  = tgtmap + NROW;                    // 512 ints: ctr1[8] + ctr2[8] @128B
  int* bincnt = flags + 512;                      // 3 counts + ml at [4] (+pad to 32)
  int* mlptr  = bincnt + 4;
  int* blist0 = bincnt + 32;                      // 8192
  int* blist1 = blist0 + NROW;                    // 8192
  int* blist2 = blist1 + NROW;                    // 8192
  float* combo = bufA;                            // 8192*384 (head 0..32 | p0 33..288 | p1 289..352 | p2 353..368)
  float* stats = bufA + (size_t)NROW*384;         // 8192*6
  float* tlog  = stats + (size_t)NROW*6;          // 8192
  float* wcat  = tlog + NROW;                     // 384*1024

  float* outF = (float*)d_out;
  hipMemsetAsync(outF, 0, sizeof(float), stream);
  hipMemsetAsync(flags, 0, 544*sizeof(int), stream);

  k_prep<<<32, 256, 0, stream>>>(length, inp_seq, tgt_seq, tokmap, tgtmap,
                                 bincnt, mlptr, blist0, blist1, blist2);
  k_emb<<<NROW, 256, 0, stream>>>(tokmap, emb, tokemb);
  k_hid<<<256, 256, 0, stream>>>(z, l2h_w, l2h_b, hb0);

  // pre0 = tokemb @ w0ih^T + b0ih + b0hh   (bf16 MFMA, A pre-gathered bf16)
  k_gemm_bf16<<<dim3(HH/128, NROW/128), 256, 0, stream>>>((const float*)tokemb, EE,
                                                          nullptr, 1, w0ih,
                                                          b0ih, b0hh, bufA, NROW, HH, EE);
  // split-role pipelined recurrence (rounds = maxlen): hbB := h2 (bf16)
  k_rnn_split<<<128, 256, 0, stream>>>(bufA, hbB, w0hh, w1ih, w1hh, b1ih, b1hh,
                                       hb0, hx, flags, mlptr);

  // single fused output GEMM: combo = h2 @ [head;p0;p1;p2]^T (A already bf16)
  k_wcat<<<384, 256, 0, stream>>>(head_w, p0, p1, p2, wcat);
  k_gemm_bf16<<<dim3(3, NROW/128), 256, 0, stream>>>((const float*)hbB, HH, nullptr, 1,
                                                     wcat, nullptr, nullptr,
                                                     combo, NROW, 384, HH);

  // cluster LSE only for rows whose TARGET is in that cluster (binned lists)
  k_cluster<<<NROW/16, 256, 0, stream>>>(combo, 33,  384, 256, tw0, 70,
                                         blist0, bincnt, 0, stats);
  k_cluster<<<NROW/16, 256, 0, stream>>>(combo, 289, 384, 64,  tw1, 900,
                                         blist1, bincnt, 1, stats);
  k_cluster<<<NROW/16, 256, 0, stream>>>(combo, 353, 384, 16,  tw2, 19000,
                                         blist2, bincnt, 2, stats);
  k_tlogit<<<NROW/4, 256, 0, stream>>>(tgtmap, combo, tw0, tw1, tw2, tlog);
  k_final<<<NROW/256, 256, 0, stream>>>(combo, stats, tlog, tgtmap, outF);
}

// Round 13
// 1460.820 us; speedup vs baseline: 1.1499x; 1.0129x over previous
//
#include <hip/hip_runtime.h>
#include <hip/hip_bf16.h>
#include <math.h>

#define BB 32
#define SS 256
#define EE 512
#define HH 1024
#define LDM 256
#define NROW (BB*SS)   // 8192

typedef __attribute__((ext_vector_type(8))) short bf16x8;
typedef __attribute__((ext_vector_type(4))) float f32x4;
typedef unsigned long long u64;

static __device__ inline unsigned short f2bf(float f){
  unsigned u = __float_as_uint(f);
  unsigned r = (u + 0x7fffu + ((u >> 16) & 1u)) >> 16;
  return (unsigned short)r;
}
// cheap round (no tie-to-even) for GEMM staging
static __device__ inline unsigned short f2bf_fast(float f){
  return (unsigned short)((__float_as_uint(f) + 0x8000u) >> 16);
}
static __device__ inline bf16x8 cvt8(float4 x, float4 y){
  union { ushort s[8]; bf16x8 v; } t;
  t.s[0]=f2bf_fast(x.x); t.s[1]=f2bf_fast(x.y); t.s[2]=f2bf_fast(x.z); t.s[3]=f2bf_fast(x.w);
  t.s[4]=f2bf_fast(y.x); t.s[5]=f2bf_fast(y.y); t.s[6]=f2bf_fast(y.z); t.s[7]=f2bf_fast(y.w);
  return t.v;
}
static __device__ inline unsigned packbf(float a, float b){
  return (unsigned)f2bf(a) | ((unsigned)f2bf(b) << 16);
}
// fast-rounded pack (bit-identical to cvt8's per-element rounding)
static __device__ inline unsigned pkfast(float a, float b){
  return (unsigned)f2bf_fast(a) | ((unsigned)f2bf_fast(b) << 16);
}

// fast tanh: 1 - 2/(e^{2x}+1)
static __device__ inline float ftanh(float x){
  float e = __expf(2.f*x);
  return 1.f - 2.f/(e + 1.f);
}

// coherent (L1/L2-bypass, LLC-read) 16B load on the NORMAL coalescing path.
// Result lands asynchronously: caller must s_waitcnt vmcnt(0) + sched_barrier
// before first use.
#define GLD(dst, p) asm volatile("global_load_dwordx4 %0, %1, off sc0 sc1" \
                                 : "=v"(dst) : "v"(p) : "memory")

static __device__ inline bf16x8 asbf(f32x4 x){
  union { f32x4 f; bf16x8 b; } u; u.f = x; return u.b;
}

// ---------------- fused prep: sort + token/target maps + maxlen + cluster bins ----
__global__ __launch_bounds__(256) void k_prep(
    const int* __restrict__ length,
    const int* __restrict__ inp_seq, const int* __restrict__ tgt_seq,
    int* __restrict__ tokmap, int* __restrict__ tgtmap,
    int* __restrict__ cnt, int* __restrict__ ml,
    int* __restrict__ l0, int* __restrict__ l1, int* __restrict__ l2)
{
  __shared__ int src_b;
  int bs = blockIdx.x, t = threadIdx.x;
  if (t < 32){
    int lb = length[t];
    int r = 0;
    for (int o = 0; o < BB; ++o){
      int lo = length[o];
      if (lo > lb || (lo == lb && o < t)) ++r;
    }
    if (r == bs) src_b = t;                  // exactly one writer (ranks are a permutation)
    if (bs == 0 && t == 0){
      int m = 0;
      for (int o = 0; o < BB; ++o){ int lo = length[o]; if (lo > m) m = lo; }
      *ml = m;
    }
  }
  __syncthreads();
  int b = src_b;
  int row = bs*SS + t;
  tokmap[row] = inp_seq[b*SS + t];
  int tgt = tgt_seq[b*SS + t];
  tgtmap[row] = tgt;
  int ci = (tgt == 0) ? -1 : (tgt >= 1000) ? 2 : (tgt >= 100) ? 1 : (tgt >= 30) ? 0 : -1;
  int lane = t & 63;
  #pragma unroll
  for (int c = 0; c < 3; ++c){
    unsigned long long mask = __ballot(ci == c);
    int nc = __popcll(mask);
    int base = 0;
    if (lane == 0 && nc) base = atomicAdd(&cnt[c], nc);
    base = __shfl(base, 0);
    if (ci == c){
      int pos = __popcll(mask & ((1ull << lane) - 1ull));
      int* lst = (c == 0) ? l0 : (c == 1) ? l1 : l2;
      lst[base + pos] = row;
    }
  }
}

// gather emb rows (sorted token order) -> bf16 tokemb[8192][512]
__global__ __launch_bounds__(256) void k_emb(
    const int* __restrict__ tokmap, const float* __restrict__ emb,
    ushort* __restrict__ tokemb)
{
  int row = blockIdx.x; int t = threadIdx.x;
  const float2* src = (const float2*)(emb + (size_t)tokmap[row]*EE);
  float2 v = src[t];
  ((unsigned*)tokemb)[(size_t)row*(EE/2) + t] = pkfast(v.x, v.y);
}

// convert w0ih [1024][512] fp32 -> bf16 (read once per GEMM instead of 8x fp32)
__global__ __launch_bounds__(256) void k_w0b(
    const float* __restrict__ w, ushort* __restrict__ wb)
{
  int row = blockIdx.x; int t = threadIdx.x;
  float2 v = ((const float2*)(w + (size_t)row*EE))[t];
  ((unsigned*)wb)[(size_t)row*(EE/2) + t] = pkfast(v.x, v.y);
}

// hid = z @ l2h_w.T + l2h_b, written DIRECTLY in bf16 fragment-major layout
__global__ __launch_bounds__(256) void k_hid(const float* __restrict__ z,
        const float* __restrict__ w, const float* __restrict__ bias,
        ushort* __restrict__ hb0){
  int id = blockIdx.x*256 + threadIdx.x;      // flat [B,2H] index = b*2048 + c
  int b = id >> 11, c = id & 2047;
  const float4* zr = (const float4*)(z + b*LDM);
  const float4* wr = (const float4*)(w + (size_t)c*LDM);
  float a0=0,a1=0,a2=0,a3=0;
  #pragma unroll 4
  for (int k=0;k<LDM/4;k++){ float4 zz=zr[k], ww=wr[k];
    a0+=zz.x*ww.x; a1+=zz.y*ww.y; a2+=zz.z*ww.z; a3+=zz.w*ww.w; }
  float val = a0+a1+a2+a3 + bias[c];
  int layer = id >> 15, bp = (id >> 10) & 31, j = id & 1023;
  hb0[(layer<<15) + ((j>>3)<<8) + (bp<<3) + (j&7)] = f2bf(val);
}

// concat [head_w(33); p0(256); p1(64); p2(16); zeros(15)] -> bf16 wcatb[384][1024]
__global__ __launch_bounds__(256) void k_wcat(
    const float* __restrict__ head_w, const float* __restrict__ p0,
    const float* __restrict__ p1, const float* __restrict__ p2,
    ushort* __restrict__ wcatb){
  int row = blockIdx.x; int t = threadIdx.x;
  unsigned* dst = (unsigned*)wcatb + (size_t)row*(HH/2) + t*2;
  const float* src;
  if      (row < 33)  src = head_w + (size_t)row*HH;
  else if (row < 289) src = p0 + (size_t)(row-33)*HH;
  else if (row < 353) src = p1 + (size_t)(row-289)*HH;
  else if (row < 369) src = p2 + (size_t)(row-353)*HH;
  else { dst[0] = 0u; dst[1] = 0u; return; }
  float4 v = ((const float4*)src)[t];
  dst[0] = pkfast(v.x, v.y);
  dst[1] = pkfast(v.z, v.w);
}

// ---------------- bf16 MFMA GEMM: C[M,N] = A[M,K] @ Bm[N,K]^T (+bias0+bias1)
// abf16/bbf16: operand already bf16 (ushort, row-major) -> staging is a copy.
__global__ __launch_bounds__(256) void k_gemm_bf16(
    const float* __restrict__ A, int lda, const int* __restrict__ rowmap, int abf16,
    const float* __restrict__ Bm, int bbf16,
    const float* __restrict__ bias0, const float* __restrict__ bias1,
    float* __restrict__ C, int M, int N, int K)
{
  __shared__ ushort As[128*72];   // pad 64->72 elems: frag reads 2-way (free)
  __shared__ ushort Bs[128*72];
  const int nt = blockIdx.x * 128, mt = blockIdx.y * 128;
  const int tid = threadIdx.x;
  const int wv = tid >> 6, ln = tid & 63;
  const int wm = wv & 1, wn = wv >> 1;          // 2x2 wave grid (64x64 each)
  const int lc = ln & 15, quad = ln >> 4;
  f32x4 acc[4][4] = {{{0.f,0.f,0.f,0.f}}};

  for (int s = 0; s < K; s += 64){
    __syncthreads();
    #pragma unroll
    for (int cc = 0; cc < 4; ++cc){
      int ch = tid*4 + cc;                 // 0..1023: row=ch>>3, chunk=ch&7
      int r = ch >> 3, c = ch & 7;
      int ar = mt + r;
      if (abf16){
        const ushort* ap = (const ushort*)A + (size_t)ar*lda + s + c*8;
        *(bf16x8*)&As[r*72 + c*8] = *(const bf16x8*)ap;
      } else {
        const float* ap = A + (size_t)(rowmap ? rowmap[ar] : ar)*lda + s + c*8;
        float4 x = *(const float4*)ap, y = *(const float4*)(ap+4);
        *(bf16x8*)&As[r*72 + c*8] = cvt8(x, y);
      }
      int br = nt + r; if (br >= N) br = N - 1;
      if (bbf16){
        const ushort* bp = (const ushort*)Bm + (size_t)br*K + s + c*8;
        *(bf16x8*)&Bs[r*72 + c*8] = *(const bf16x8*)bp;
      } else {
        const float* bp = Bm + (size_t)br*K + s + c*8;
        float4 bx = *(const float4*)bp, by = *(const float4*)(bp+4);
        *(bf16x8*)&Bs[r*72 + c*8] = cvt8(bx, by);
      }
    }
    __syncthreads();
    #pragma unroll
    for (int kq = 0; kq < 2; ++kq){
      int cq = kq*4 + quad;
      bf16x8 af[4], bfv[4];
      #pragma unroll
      for (int i=0;i<4;i++) af[i]  = *(const bf16x8*)&As[(wm*64 + i*16 + lc)*72 + cq*8];
      #pragma unroll
      for (int j=0;j<4;j++) bfv[j] = *(const bf16x8*)&Bs[(wn*64 + j*16 + lc)*72 + cq*8];
      #pragma unroll
      for (int i=0;i<4;i++)
        #pragma unroll
        for (int j=0;j<4;j++)
          acc[i][j] = __builtin_amdgcn_mfma_f32_16x16x32_bf16(af[i], bfv[j], acc[i][j], 0, 0, 0);
    }
  }
  #pragma unroll
  for (int j=0;j<4;j++){
    int col = nt + wn*64 + j*16 + lc;
    if (col < N){
      float badd = (bias0 ? bias0[col] : 0.f) + (bias1 ? bias1[col] : 0.f);
      #pragma unroll
      for (int i=0;i<4;i++){
        int row = mt + wm*64 + i*16 + quad*4;
        #pragma unroll
        for (int r=0;r<4;r++)
          C[(size_t)(row+r)*N + col] = acc[i][j][r] + badd;
      }
    }
  }
}

// ---------------- split-role pipelined persistent RNN recurrence ----------------
// EXACT R12 structure (proven, 941us @ ml-bounded rounds). No changes.
__global__ __launch_bounds__(256, 1) void k_rnn_split(
    const float* __restrict__ pre0, ushort* __restrict__ h2out,
    const float* __restrict__ w0hh, const float* __restrict__ w1ih,
    const float* __restrict__ w1hh,
    const float* __restrict__ b1ih, const float* __restrict__ b1hh,
    const ushort* __restrict__ hb0, ushort* __restrict__ hx, int* flags,
    const int* __restrict__ mlp)
{
  __shared__ ushort w0F[16384], wiF[16384], whF[16384];  // frag-order weight slices
  __shared__ float red[2176];                            // [wv][row 0..31][17]
  const int wg  = blockIdx.x;
  const int tid = threadIdx.x;
  const bool roleL2 = wg >= 64;
  const int cw  = roleL2 ? wg - 64 : wg;
  const int j0  = cw * 16;
  const int ml  = *mlp;
  int* myctr = flags + (roleL2 ? 256 : 0) + (cw & 7) * 32;

  // stage this role's 16x1024 weight slices as bf16 in MFMA fragment order
  for (int c = tid; c < 4096; c += 256){
    int rr = c >> 8, cc = (c & 255) * 4;
    int dst = ((cc >> 3)*16 + rr)*8 + (cc & 7);
    size_t srow = (size_t)(j0 + rr)*HH + cc;
    float4 w4; uint2 p;
    if (!roleL2){
      w4 = *(const float4*)&w0hh[srow];
      p.x = packbf(w4.x, w4.y); p.y = packbf(w4.z, w4.w);
      *(uint2*)&w0F[dst] = p;
    } else {
      w4 = *(const float4*)&w1ih[srow];
      p.x = packbf(w4.x, w4.y); p.y = packbf(w4.z, w4.w);
      *(uint2*)&wiF[dst] = p;
      w4 = *(const float4*)&w1hh[srow];
      p.x = packbf(w4.x, w4.y); p.y = packbf(w4.z, w4.w);
      *(uint2*)&whF[dst] = p;
    }
  }
  const int lane = tid & 63, wv = tid >> 6;
  const int col = lane & 15, quad = lane >> 4;
  const int ob = tid >> 3, oj = (tid << 1) & 15;
  const int ro = ob*17 + oj;
  const int k = j0 + oj;
  const unsigned off = ((unsigned)(k >> 3) << 7) + ((unsigned)ob << 2) + ((unsigned)(k & 7) >> 1);
  ushort* h1buf = hx;                 // 3 x 32768
  ushort* h2buf = hx + 3*32768;       // 2 x 32768

  if (!roleL2){
    // ---------------- role L1: the h1 chain ----------------
    float2 pre = *(const float2*)&pre0[((size_t)ob*SS + 0)*HH + j0 + oj];
    __syncthreads();
    for (int t = 0; t < ml; ++t){
      const u64* s1 = (const u64*)(t == 0 ? hb0 : h1buf + ((t+2)%3)*32768);
      f32x4 a0r[8], a1r[8];
      #pragma unroll
      for (int ks = 0; ks < 8; ++ks){
        int kb = wv*32 + ks*4 + quad;
        const u64* p = s1 + (kb << 6) + (col << 1);
        GLD(a0r[ks], p);
        GLD(a1r[ks], p + 32);
      }
      asm volatile("s_waitcnt vmcnt(0)" ::: "memory");
      __builtin_amdgcn_sched_barrier(0);

      f32x4 acc0 = {0.f,0.f,0.f,0.f}, acc1 = {0.f,0.f,0.f,0.f};
      #pragma unroll
      for (int ks = 0; ks < 8; ++ks){
        int kb = wv*32 + ks*4 + quad;
        bf16x8 b0 = *(const bf16x8*)&w0F[(kb*16 + col)*8];
        acc0 = __builtin_amdgcn_mfma_f32_16x16x32_bf16(asbf(a0r[ks]), b0, acc0, 0, 0, 0);
        acc1 = __builtin_amdgcn_mfma_f32_16x16x32_bf16(asbf(a1r[ks]), b0, acc1, 0, 0, 0);
      }
      #pragma unroll
      for (int q = 0; q < 4; ++q){
        red[wv*544 + (quad*4 + q)*17 + col]      = acc0[q];
        red[wv*544 + (16 + quad*4 + q)*17 + col] = acc1[q];
      }
      __syncthreads();
      float s0 = red[ro]   + red[544 + ro]   + red[1088 + ro]   + red[1632 + ro];
      float s1v= red[ro+1] + red[544 + ro+1] + red[1088 + ro+1] + red[1632 + ro+1];
      unsigned pk = packbf(ftanh(pre.x + s0), ftanh(pre.y + s1v));
      __hip_atomic_store((unsigned*)(h1buf + (t%3)*32768) + off, pk,
                         __ATOMIC_RELAXED, __HIP_MEMORY_SCOPE_AGENT);
      asm volatile("s_waitcnt vmcnt(0)" ::: "memory");
      __syncthreads();
      if (tid == 0)
        __hip_atomic_fetch_add(myctr, 1, __ATOMIC_RELAXED, __HIP_MEMORY_SCOPE_AGENT);

      int tn = (t + 1 < ml) ? t + 1 : ml - 1;
      pre = *(const float2*)&pre0[((size_t)ob*SS + tn)*HH + j0 + oj];

      if (t < ml - 1 && tid < 16){
        int tv = (tid < 8) ? 8*(t+1) : 8*(t-1);
        const int* fp = flags + ((tid < 8) ? 0 : 256) + (tid & 7)*32;
        if (tv > 0)
          while (__hip_atomic_load(fp, __ATOMIC_RELAXED, __HIP_MEMORY_SCOPE_AGENT) < tv) {}
      }
      __syncthreads();
    }
  } else {
    // ---------------- role L2: the h2 chain (one step behind) ----------------
    float2 pre2;
    pre2.x = b1ih[j0+oj]   + b1hh[j0+oj];
    pre2.y = b1ih[j0+oj+1] + b1hh[j0+oj+1];
    __syncthreads();
    // pre-loop gate: h1[0] fully stored
    if (tid < 8){
      while (__hip_atomic_load(flags + tid*32, __ATOMIC_RELAXED,
                               __HIP_MEMORY_SCOPE_AGENT) < 8) {}
    }
    __syncthreads();
    for (int s = 0; s < ml; ++s){
      const u64* sa = (const u64*)(h1buf + (s%3)*32768);                  // h1[s]
      const u64* sc = (const u64*)(s == 0 ? hb0 + 32768
                                          : h2buf + ((s+1)&1)*32768);     // h2[s-1]
      f32x4 a0r[8], a1r[8], c0r[8], c1r[8];
      #pragma unroll
      for (int ks = 0; ks < 8; ++ks){
        int kb = wv*32 + ks*4 + quad;
        const u64* p = sa + (kb << 6) + (col << 1);
        GLD(a0r[ks], p);
        GLD(a1r[ks], p + 32);
      }
      #pragma unroll
      for (int ks = 0; ks < 8; ++ks){
        int kb = wv*32 + ks*4 + quad;
        const u64* p = sc + (kb << 6) + (col << 1);
        GLD(c0r[ks], p);
        GLD(c1r[ks], p + 32);
      }
      asm volatile("s_waitcnt vmcnt(0)" ::: "memory");
      __builtin_amdgcn_sched_barrier(0);

      f32x4 acc0 = {0.f,0.f,0.f,0.f}, acc1 = {0.f,0.f,0.f,0.f};
      #pragma unroll
      for (int ks = 0; ks < 8; ++ks){
        int kb = wv*32 + ks*4 + quad;
        bf16x8 bi = *(const bf16x8*)&wiF[(kb*16 + col)*8];
        acc0 = __builtin_amdgcn_mfma_f32_16x16x32_bf16(asbf(a0r[ks]), bi, acc0, 0, 0, 0);
        acc1 = __builtin_amdgcn_mfma_f32_16x16x32_bf16(asbf(a1r[ks]), bi, acc1, 0, 0, 0);
        bf16x8 bh = *(const bf16x8*)&whF[(kb*16 + col)*8];
        acc0 = __builtin_amdgcn_mfma_f32_16x16x32_bf16(asbf(c0r[ks]), bh, acc0, 0, 0, 0);
        acc1 = __builtin_amdgcn_mfma_f32_16x16x32_bf16(asbf(c1r[ks]), bh, acc1, 0, 0, 0);
      }
      #pragma unroll
      for (int q = 0; q < 4; ++q){
        red[wv*544 + (quad*4 + q)*17 + col]      = acc0[q];
        red[wv*544 + (16 + quad*4 + q)*17 + col] = acc1[q];
      }
      __syncthreads();
      float s2v = red[ro]   + red[544 + ro]   + red[1088 + ro]   + red[1632 + ro];
      float s3v = red[ro+1] + red[544 + ro+1] + red[1088 + ro+1] + red[1632 + ro+1];
      unsigned pk2 = packbf(ftanh(pre2.x + s2v), ftanh(pre2.y + s3v));
      __hip_atomic_store((unsigned*)(h2buf + (s&1)*32768) + off, pk2,
                         __ATOMIC_RELAXED, __HIP_MEMORY_SCOPE_AGENT);
      asm volatile("s_waitcnt vmcnt(0)" ::: "memory");
      __syncthreads();
      if (tid == 0)
        __hip_atomic_fetch_add(myctr, 1, __ATOMIC_RELAXED, __HIP_MEMORY_SCOPE_AGENT);

      // off-protocol (cached): bf16 h2 for the downstream combo GEMM
      *((unsigned*)h2out + (((size_t)ob*SS + s)*HH + j0 + oj) / 2) = pk2;

      if (s < ml - 1 && tid < 16){
        int tv = (tid < 8) ? 8*(s+2) : 8*(s+1);
        const int* fp = flags + ((tid < 8) ? 0 : 256) + (tid & 7)*32;
        while (__hip_atomic_load(fp, __ATOMIC_RELAXED, __HIP_MEMORY_SCOPE_AGENT) < tv) {}
      }
      __syncthreads();
    }
  }
}

// ---------------- cluster logsumexp over the BINNED row list (4 rows/wave) ----
__global__ __launch_bounds__(256) void k_cluster(
    const float* __restrict__ combo, int off, int ld, int Kp,
    const float* __restrict__ W, int Nc,
    const int* __restrict__ rowlist, const int* __restrict__ cntp, int ci,
    float* __restrict__ stats)
{
  __shared__ float ps[4][4][256];
  int lane = threadIdx.x & 63;
  int wvl  = threadIdx.x >> 6;
  int n0 = (blockIdx.x*4 + wvl) * 4;
  int count = cntp[ci];
  int rows[4];
  #pragma unroll
  for (int r=0;r<4;r++){
    rows[r] = (n0 + r < count) ? rowlist[n0 + r] : -1;
    if (rows[r] >= 0)
      for (int k=lane;k<Kp;k+=64)
        ps[wvl][r][k] = combo[(size_t)rows[r]*ld + off + k];
  }
  __syncthreads();
  if (rows[0] < 0) return;          // list is compact: all 4 invalid together

  float mx[4], sm[4];
  #pragma unroll
  for (int r=0;r<4;r++){ mx[r]=-1e30f; sm[r]=0.f; }
  for (int n=lane; n<Nc; n+=64){
    const float* wr = W + (size_t)n*Kp;
    float l[4]={0.f,0.f,0.f,0.f};
    for (int k=0;k<Kp;k+=4){
      float4 w4 = *(const float4*)(wr+k);
      #pragma unroll
      for (int r=0;r<4;r++){
        l[r] += w4.x*ps[wvl][r][k] + w4.y*ps[wvl][r][k+1]
              + w4.z*ps[wvl][r][k+2] + w4.w*ps[wvl][r][k+3];
      }
    }
    #pragma unroll
    for (int r=0;r<4;r++){
      float nm = fmaxf(mx[r], l[r]);
      sm[r] = sm[r]*__expf(mx[r]-nm) + __expf(l[r]-nm);
      mx[r] = nm;
    }
  }
  #pragma unroll
  for (int r=0;r<4;r++){
    for (int off2=32; off2; off2>>=1){
      float om = __shfl_down(mx[r], off2);
      float os = __shfl_down(sm[r], off2);
      float nm = fmaxf(mx[r], om);
      sm[r] = sm[r]*__expf(mx[r]-nm) + os*__expf(om-nm);
      mx[r] = nm;
    }
    if (lane==0 && rows[r] >= 0){
      stats[(size_t)rows[r]*6 + ci*2 + 0] = mx[r];
      stats[(size_t)rows[r]*6 + ci*2 + 1] = sm[r];
    }
  }
}

// ---------------- target logit for tail clusters (one wave per row) ----------------
__global__ __launch_bounds__(256) void k_tlogit(
    const int* __restrict__ tgtmap, const float* __restrict__ combo,
    const float* __restrict__ w0, const float* __restrict__ w1, const float* __restrict__ w2,
    float* __restrict__ tlogit)
{
  int lane = threadIdx.x & 63;
  int row = (blockIdx.x * 256 + threadIdx.x) >> 6;
  int tgt = tgtmap[row];
  float acc = 0.f;
  const float* pr = nullptr; const float* wr = nullptr; int Kp = 0;
  const float* crow = combo + (size_t)row*384;
  if      (tgt >= 1000){ pr = crow + 353; wr = w2 + (size_t)(tgt-1000)*16;  Kp=16;  }
  else if (tgt >= 100) { pr = crow + 289; wr = w1 + (size_t)(tgt-100)*64;   Kp=64;  }
  else if (tgt >= 30)  { pr = crow + 33;  wr = w0 + (size_t)(tgt-30)*256;   Kp=256; }
  for (int k=lane; k<Kp; k+=64) acc += pr[k]*wr[k];
  for (int off=32; off; off>>=1) acc += __shfl_down(acc, off);
  if (lane==0) tlogit[row] = acc;
}

// ---------------- final: head LSE + assemble NLL, reduce ----------------
__global__ __launch_bounds__(256) void k_final(
    const float* __restrict__ combo, const float* __restrict__ stats,
    const float* __restrict__ tlogit, const int* __restrict__ tgtmap,
    float* __restrict__ out)
{
  int row = blockIdx.x*256 + threadIdx.x;
  int tgt = tgtmap[row];
  float nll = 0.f;
  if (tgt != 0){
    const float* hrow = combo + (size_t)row*384;
    float m = hrow[0];
    #pragma unroll
    for (int i=1;i<33;i++) m = fmaxf(m, hrow[i]);
    float s = 0.f;
    #pragma unroll
    for (int i=0;i<33;i++) s += __expf(hrow[i]-m);
    float lse = __logf(s) + m;
    int ci = (tgt>=1000) ? 2 : (tgt>=100) ? 1 : (tgt>=30) ? 0 : -1;
    if (ci < 0){
      nll = lse - hrow[tgt];
    } else {
      float cm = stats[(size_t)row*6 + ci*2 + 0];
      float cs = stats[(size_t)row*6 + ci*2 + 1];
      nll = lse - hrow[30+ci] + (__logf(cs) + cm - tlogit[row]);
    }
  }
  float v = nll;
  for (int off=32; off; off>>=1) v += __shfl_down(v, off);
  __shared__ float wsum[4];
  int lane = threadIdx.x & 63, wv = threadIdx.x >> 6;
  if (lane==0) wsum[wv] = v;
  __syncthreads();
  if (threadIdx.x==0) atomicAdd(out, wsum[0]+wsum[1]+wsum[2]+wsum[3]);
}

extern "C" void kernel_launch(void* const* d_in, const int* in_sizes, int n_in,
                              void* d_out, int out_size, void* d_ws, size_t ws_size,
                              hipStream_t stream)
{
  const float* z      = (const float*)d_in[0];
  const float* emb    = (const float*)d_in[1];
  const float* l2h_w  = (const float*)d_in[2];
  const float* l2h_b  = (const float*)d_in[3];
  const float* w0ih   = (const float*)d_in[4];
  const float* w0hh   = (const float*)d_in[5];
  const float* b0ih   = (const float*)d_in[6];
  const float* b0hh   = (const float*)d_in[7];
  const float* w1ih   = (const float*)d_in[8];
  const float* w1hh   = (const float*)d_in[9];
  const float* b1ih   = (const float*)d_in[10];
  const float* b1hh   = (const float*)d_in[11];
  const float* head_w = (const float*)d_in[12];
  const float* p0     = (const float*)d_in[13];
  const float* tw0    = (const float*)d_in[14];
  const float* p1     = (const float*)d_in[15];
  const float* tw1    = (const float*)d_in[16];
  const float* p2     = (const float*)d_in[17];
  const float* tw2    = (const float*)d_in[18];
  const int* inp_seq  = (const int*)d_in[19];
  const int* tgt_seq  = (const int*)d_in[20];
  const int* length   = (const int*)d_in[21];

  float* ws   = (float*)d_ws;
  ushort* hb0 = (ushort*)ws;                      // 65536 ushorts (2 layers initial)
  ushort* hx  = hb0 + 65536;                      // 163840 ushorts: h1 x3, h2 x2
  float* bufA = ws + 114688;                      // 8192*1024 fp32 (pre0; later combo etc.)
  ushort* hbB = (ushort*)(bufA + (size_t)NROW*HH); // 8192*1024 bf16 (h2)
  ushort* tokemb = hbB + (size_t)NROW*HH;         // 8192*512 bf16 (gathered emb)
  ushort* w0b = tokemb + (size_t)NROW*EE;         // 1024*512 bf16 (w0ih)
  ushort* wcatb = w0b + (size_t)HH*EE;            // 384*1024 bf16 (concat weights)
  int*   ibuf = (int*)(wcatb + 384*HH);
  int* tokmap = ibuf + 32;                        // 8192
  int* tgtmap = tokmap + NROW;                    // 8192
  int* flags  = tgtmap + NROW;                    // 512 ints: ctr1[8] + ctr2[8] @128B
  int* bincnt = flags + 512;                      // 3 counts + ml at [4] (+pad to 32)
  int* mlptr  = bincnt + 4;
  int* blist0 = bincnt + 32;                      // 8192
  int* blist1 = blist0 + NROW;                    // 8192
  int* blist2 = blist1 + NROW;                    // 8192
  float* combo = bufA;                            // 8192*384 (head 0..32 | p0 33..288 | p1 289..352 | p2 353..368)
  float* stats = bufA + (size_t)NROW*384;         // 8192*6
  float* tlog  = stats + (size_t)NROW*6;          // 8192

  float* outF = (float*)d_out;
  hipMemsetAsync(outF, 0, sizeof(float), stream);
  hipMemsetAsync(flags, 0, 544*sizeof(int), stream);

  k_prep<<<32, 256, 0, stream>>>(length, inp_seq, tgt_seq, tokmap, tgtmap,
                                 bincnt, mlptr, blist0, blist1, blist2);
  k_emb<<<NROW, 256, 0, stream>>>(tokmap, emb, tokemb);
  k_w0b<<<HH, 256, 0, stream>>>(w0ih, w0b);
  k_hid<<<256, 256, 0, stream>>>(z, l2h_w, l2h_b, hb0);
  k_wcat<<<384, 256, 0, stream>>>(head_w, p0, p1, p2, wcatb);

  // pre0 = tokemb @ w0ih^T + b0ih + b0hh   (bf16 MFMA, both operands bf16)
  k_gemm_bf16<<<dim3(HH/128, NROW/128), 256, 0, stream>>>((const float*)tokemb, EE,
                                                          nullptr, 1,
                                                          (const float*)w0b, 1,
                                                          b0ih, b0hh, bufA, NROW, HH, EE);
  // split-role pipelined recurrence (rounds = maxlen): hbB := h2 (bf16)
  k_rnn_split<<<128, 256, 0, stream>>>(bufA, hbB, w0hh, w1ih, w1hh, b1ih, b1hh,
                                       hb0, hx, flags, mlptr);

  // single fused output GEMM: combo = h2 @ [head;p0;p1;p2]^T (both operands bf16)
  k_gemm_bf16<<<dim3(3, NROW/128), 256, 0, stream>>>((const float*)hbB, HH, nullptr, 1,
                                                     (const float*)wcatb, 1,
                                                     nullptr, nullptr,
                                                     combo, NROW, 384, HH);

  // cluster LSE only for rows whose TARGET is in that cluster (binned lists)
  k_cluster<<<NROW/16, 256, 0, stream>>>(combo, 33,  384, 256, tw0, 70,
                                         blist0, bincnt, 0, stats);
  k_cluster<<<NROW/16, 256, 0, stream>>>(combo, 289, 384, 64,  tw1, 900,
                                         blist1, bincnt, 1, stats);
  k_cluster<<<NROW/16, 256, 0, stream>>>(combo, 353, 384, 16,  tw2, 19000,
                                         blist2, bincnt, 2, stats);
  k_tlogit<<<NROW/4, 256, 0, stream>>>(tgtmap, combo, tw0, tw1, tw2, tlog);
  k_final<<<NROW/256, 256, 0, stream>>>(combo, stats, tlog, tgtmap, outF);
}